// Round 17
// baseline (240.444 us; speedup 1.0000x reference)
//
#include <hip/hip_runtime.h>
#include <hip/hip_bf16.h>
#include <math.h>

#define S_TOT 262144   // 64^3
#define EPS_F 1e-5f
#define NPART 512      // pool partial-K blocks
#define PL    8656     // LDS plane stride in shorts (17312B ≡ 32B mod 128)

typedef __attribute__((ext_vector_type(8))) short s16x8;
typedef __attribute__((ext_vector_type(4))) float f32x4;
typedef __attribute__((ext_vector_type(4))) unsigned u32x4;

__device__ __forceinline__ unsigned short f2bf(float f) {   // RNE, manual (prep only)
    unsigned u = __builtin_bit_cast(unsigned, f);
    unsigned r = (u + 0x7FFFu + ((u >> 16) & 1u)) >> 16;
    return (unsigned short)r;
}
__device__ __forceinline__ float bf2f(unsigned short u) {
    return __builtin_bit_cast(float, ((unsigned)u) << 16);
}
// HW packed convert: low16 = bf16(a), high16 = bf16(b), RNE.
__device__ __forceinline__ unsigned cvt_pk_bf16(float a, float b) {
    unsigned r;
    asm("v_cvt_pk_bf16_f32 %0, %1, %2" : "=v"(r) : "v"(a), "v"(b));
    return r;
}

// ---------------------------------------------------------------------------
// Weight prep.
// Layer 0: w0[hi|lo][brow][k=tap(32,pad0)] at wpad[0..2047]  (hi+lo used).
// Layers 1-3: PACKED hi-only at whp[(layer-1)*27648 + tap*1024 + brow*32 + cin].
// brow(cout) = ((cout&1)<<4) | (cout>>1).
// ---------------------------------------------------------------------------
__global__ __launch_bounds__(256)
void prep_w_k(const float* __restrict__ conv0_w, const float* __restrict__ convs_w,
              unsigned short* __restrict__ wpad, unsigned short* __restrict__ whp)
{
    int idx = blockIdx.x * 256 + threadIdx.x;
    if (idx < 2048) {
        int brow = idx >> 5, k = idx & 31;
        int cout = 2 * (brow & 15) + (brow >> 4);
        float wv = (k < 27) ? conv0_w[cout * 27 + k] : 0.f;
        unsigned short hi = f2bf(wv);
        unsigned short lo = f2bf(wv - bf2f(hi));
        wpad[brow * 32 + k]        = hi;
        wpad[1024 + brow * 32 + k] = lo;
        return;
    }
    int j = idx - 2048;
    if (j >= 3 * 27648) return;
    int layer = j / 27648 + 1;
    int rem   = j % 27648;
    int tap   = rem >> 10;
    int cout  = (rem >> 5) & 31;
    int cin   = rem & 31;
    float wv = convs_w[(((layer - 1) * 32 + cout) * 32 + cin) * 27 + tap];
    unsigned short hi = f2bf(wv);
    int brow = ((cout & 1) << 4) | (cout >> 1);
    whp[(size_t)(layer - 1) * 27648 + tap * 1024 + brow * 32 + cin] = hi;
}

// ---------------------------------------------------------------------------
// Layer 0: cin=1 im2col over taps (K = 27 taps padded to 32), hi+lo.
// 512 blocks (8x8x16 slab), 512 threads, wave wv owns z-planes {2wv,2wv+1}.
// ---------------------------------------------------------------------------
__global__ __launch_bounds__(512, 2)
void conv0_k(const float* __restrict__ in, const unsigned short* __restrict__ w0,
             unsigned short* __restrict__ outb, float* __restrict__ raw_out)
{
    __shared__ unsigned short sc[1824];
    __shared__ float s_red[512];

    const int tid  = threadIdx.x;
    const int lane = tid & 63;
    const int wv   = tid >> 6;
    const int row  = lane & 15;
    const int g4   = lane >> 4;

    const int blk = blockIdx.x;
    const int b   = blk >> 8;
    const int t   = blk & 255;
    const int x0  = (t & 7) << 3;
    const int y0  = ((t >> 3) & 7) << 3;
    const int z0  = (t >> 6) << 4;

    for (int i = tid; i < 1800; i += 512) {
        int zz = i / 100, r2 = i - zz * 100, yy = r2 / 10, xx = r2 - yy * 10;
        int gz = z0 + zz - 1, gy = y0 + yy - 1, gx = x0 + xx - 1;
        float v = 0.f;
        if ((unsigned)gz < 64u && (unsigned)gy < 64u && (unsigned)gx < 64u)
            v = in[((size_t)b << 18) + (gz << 12) + (gy << 6) + gx];
        sc[i] = (unsigned short)cvt_pk_bf16(v, v);
    }
    __syncthreads();

    int dvox[8];
    #pragma unroll
    for (int j = 0; j < 8; ++j) {
        int tap = g4 * 8 + j;
        if (tap < 27) {
            int dz = tap / 9, r9 = tap - dz * 9, dy = r9 / 3, dx = r9 - dy * 3;
            dvox[j] = dz * 100 + dy * 10 + dx;
        } else dvox[j] = 0;
    }

    s16x8 wh0 = *(const s16x8*)(w0 + row * 32 + g4 * 8);
    s16x8 wh1 = *(const s16x8*)(w0 + (16 + row) * 32 + g4 * 8);
    s16x8 wl0 = *(const s16x8*)(w0 + 1024 + row * 32 + g4 * 8);
    s16x8 wl1 = *(const s16x8*)(w0 + 1024 + (16 + row) * 32 + g4 * 8);

    f32x4 acc[2][4][2] = {};
    #pragma unroll
    for (int pl = 0; pl < 2; ++pl) {
        #pragma unroll
        for (int f = 0; f < 4; ++f) {
            int vvx = f * 16 + row;
            int base = (2 * wv + pl) * 100 + (vvx >> 3) * 10 + (vvx & 7);
            s16x8 a;
            #pragma unroll
            for (int j = 0; j < 8; ++j) a[j] = (short)sc[base + dvox[j]];
            acc[pl][f][0] = __builtin_amdgcn_mfma_f32_16x16x32_bf16(a, wh0, acc[pl][f][0], 0, 0, 0);
            acc[pl][f][0] = __builtin_amdgcn_mfma_f32_16x16x32_bf16(a, wl0, acc[pl][f][0], 0, 0, 0);
            acc[pl][f][1] = __builtin_amdgcn_mfma_f32_16x16x32_bf16(a, wh1, acc[pl][f][1], 0, 0, 0);
            acc[pl][f][1] = __builtin_amdgcn_mfma_f32_16x16x32_bf16(a, wl1, acc[pl][f][1], 0, 0, 0);
        }
    }

    {
        float s0 = 0.f, ss0 = 0.f, s1 = 0.f, ss1 = 0.f;
        #pragma unroll
        for (int pl = 0; pl < 2; ++pl)
            #pragma unroll
            for (int f = 0; f < 4; ++f)
                #pragma unroll
                for (int q = 0; q < 4; ++q) {
                    float v0 = acc[pl][f][0][q], v1 = acc[pl][f][1][q];
                    s0 += v0; ss0 += v0 * v0; s1 += v1; ss1 += v1 * v1;
                }
        s0 += __shfl_xor(s0, 16); s0 += __shfl_xor(s0, 32);
        ss0 += __shfl_xor(ss0, 16); ss0 += __shfl_xor(ss0, 32);
        s1 += __shfl_xor(s1, 16); s1 += __shfl_xor(s1, 32);
        ss1 += __shfl_xor(ss1, 16); ss1 += __shfl_xor(ss1, 32);
        if (lane < 16) {
            s_red[(wv * 32 + 2 * row) * 2]         = s0;
            s_red[(wv * 32 + 2 * row) * 2 + 1]     = ss0;
            s_red[(wv * 32 + 2 * row + 1) * 2]     = s1;
            s_red[(wv * 32 + 2 * row + 1) * 2 + 1] = ss1;
        }
    }

    #pragma unroll
    for (int pl = 0; pl < 2; ++pl) {
        int zp = 2 * wv + pl;
        unsigned short* ob = outb
            + ((((size_t)b << 18) + ((size_t)(z0 + zp) << 12) + (y0 << 6) + x0) << 5)
            + (row << 1);
        #pragma unroll
        for (int f = 0; f < 4; ++f) {
            #pragma unroll
            for (int qq = 0; qq < 4; ++qq) {
                int u = g4 * 4 + qq;
                int yy = f * 2 + (u >> 3), xx = u & 7;
                unsigned pk = cvt_pk_bf16(acc[pl][f][0][qq], acc[pl][f][1][qq]);
                *(unsigned*)(ob + ((yy << 6) + xx) * 32) = pk;
            }
        }
    }

    __syncthreads();
    if (tid < 64) {
        int n = tid & 31, sel = tid >> 5;
        float tot = 0.f;
        #pragma unroll
        for (int w = 0; w < 8; ++w) tot += s_red[(w * 32 + n) * 2 + sel];
        atomicAdd(&raw_out[(b * 32 + n) * 2 + sel], tot);
    }
}

// ---------------------------------------------------------------------------
// Mid conv layers: 16x4x8 X-WIDE tile (halo 18x6x10 = 1080 vox, 69KB LDS ->
// 2 RESIDENT blocks/CU = 4 waves/SIMD with cross-block desync).  Wave =
// z-plane, 4 frags/wave (frag = y-row of 16 consecutive x-voxels) -> every
// A ds_read_b128 16-lane phase is one contiguous 256B run (conflict-free).
// HI-ONLY packed weights + prefetch; stats fused; cvt_pk converts.
// ---------------------------------------------------------------------------
__global__ __launch_bounds__(512, 4)
void conv_slab_k(const unsigned short* __restrict__ in, const unsigned short* __restrict__ whp_l,
                 const float* __restrict__ raw_in, unsigned short* __restrict__ outb,
                 float* __restrict__ raw_out)
{
    __shared__ unsigned short tile[4 * PL];   // 69,248 B -> 2 blocks/CU
    __shared__ float s_red[512];

    const int tid  = threadIdx.x;
    const int lane = tid & 63;
    const int wv   = tid >> 6;        // wave = z-plane 0..7
    const int row  = lane & 15;       // A: x within frag; C: cout-brow
    const int g4   = lane >> 4;       // k-chunk / x-quarter
    const int g    = tid & 3;
    const int vox0 = tid >> 2;        // 0..127

    const int blk = blockIdx.x;
    const int b   = blk >> 9;
    const int t   = blk & 511;        // 4 x * 16 y * 8 z = 512 tiles/batch
    const int x0  = (t & 3) << 4;
    const int y0  = ((t >> 2) & 15) << 2;
    const int z0  = (t >> 6) << 3;

    // ---- stage halo 18x6x10 (norm+relu fused, cvt_pk) ----
    {
        float rs[8], sh[8];
        #pragma unroll
        for (int j = 0; j < 8; ++j) {
            int c = b * 32 + g * 8 + j;
            float sm = raw_in[c * 2], sq = raw_in[c * 2 + 1];
            float mean = sm * (1.f / 262144.f);
            float var  = sq * (1.f / 262144.f) - mean * mean;
            float r = rsqrtf(var + EPS_F);
            rs[j] = r; sh[j] = -mean * r;
        }
        #pragma unroll 1
        for (int u = 0; u < 9; ++u) {
            int vox = vox0 + u * 128;
            if (vox >= 1080) break;
            int zz = vox / 108, r2 = vox - zz * 108, yy = r2 / 18, xx = r2 - yy * 18;
            int gz = z0 + zz - 1, gy = y0 + yy - 1, gx = x0 + xx - 1;
            u32x4 w = (u32x4)0;
            if ((unsigned)gz < 64u && (unsigned)gy < 64u && (unsigned)gx < 64u) {
                u32x4 rv = *(const u32x4*)(in
                    + ((((size_t)b << 18) + (gz << 12) + (gy << 6) + gx) << 5) + (g << 3));
                #pragma unroll
                for (int k = 0; k < 4; ++k) {
                    float ve = __builtin_bit_cast(float, rv[k] << 16);
                    float vo = __builtin_bit_cast(float, rv[k] & 0xFFFF0000u);
                    float ne = fmaxf(0.f, fmaf(ve, rs[2 * k],     sh[2 * k]));
                    float no = fmaxf(0.f, fmaf(vo, rs[2 * k + 1], sh[2 * k + 1]));
                    w[k] = cvt_pk_bf16(ne, no);
                }
            }
            *(u32x4*)&tile[g * PL + (vox << 3)] = w;
        }
    }
    __syncthreads();

    // ---- MFMA: 27 taps x 4 frags; A reads contiguous 256B per 16-lane phase
    f32x4 acc[4][2] = {};
    {
        const unsigned short* aplane = &tile[g4 * PL];
        int abase[4];
        #pragma unroll
        for (int fr = 0; fr < 4; ++fr)
            abase[fr] = ((wv * 108 + fr * 18 + row) << 3);
        const unsigned short* wrow = whp_l + row * 32 + g4 * 8;

        s16x8 wh0 = *(const s16x8*)(wrow);
        s16x8 wh1 = *(const s16x8*)(wrow + 512);

        #pragma unroll 1
        for (int tap = 0; tap < 27; ++tap) {
            int ntap = (tap < 26) ? tap + 1 : 26;
            const unsigned short* wn = wrow + ntap * 1024;
            s16x8 nh0 = *(const s16x8*)(wn);
            s16x8 nh1 = *(const s16x8*)(wn + 512);

            int dz = tap / 9, r9 = tap - dz * 9, dy = r9 / 3, dx = r9 - dy * 3;
            int doff = ((dz * 108 + dy * 18 + dx) << 3);
            #pragma unroll
            for (int fr = 0; fr < 4; ++fr) {
                s16x8 a = *(const s16x8*)&aplane[abase[fr] + doff];
                acc[fr][0] = __builtin_amdgcn_mfma_f32_16x16x32_bf16(a, wh0, acc[fr][0], 0, 0, 0);
                acc[fr][1] = __builtin_amdgcn_mfma_f32_16x16x32_bf16(a, wh1, acc[fr][1], 0, 0, 0);
            }
            wh0 = nh0; wh1 = nh1;
        }
    }

    // ---- instance-norm partial stats ----
    {
        float s0 = 0.f, ss0 = 0.f, s1 = 0.f, ss1 = 0.f;
        #pragma unroll
        for (int fr = 0; fr < 4; ++fr)
            #pragma unroll
            for (int q = 0; q < 4; ++q) {
                float v0 = acc[fr][0][q], v1 = acc[fr][1][q];
                s0 += v0; ss0 += v0 * v0; s1 += v1; ss1 += v1 * v1;
            }
        s0 += __shfl_xor(s0, 16); s0 += __shfl_xor(s0, 32);
        ss0 += __shfl_xor(ss0, 16); ss0 += __shfl_xor(ss0, 32);
        s1 += __shfl_xor(s1, 16); s1 += __shfl_xor(s1, 32);
        ss1 += __shfl_xor(ss1, 16); ss1 += __shfl_xor(ss1, 32);
        if (lane < 16) {
            s_red[(wv * 32 + 2 * row) * 2]         = s0;
            s_red[(wv * 32 + 2 * row) * 2 + 1]     = ss0;
            s_red[(wv * 32 + 2 * row + 1) * 2]     = s1;
            s_red[(wv * 32 + 2 * row + 1) * 2 + 1] = ss1;
        }
    }

    // ---- packed channel-pair stores: voxel x = g4*4+qq, y = fr, z = wv ----
    #pragma unroll
    for (int fr = 0; fr < 4; ++fr) {
        unsigned short* ob = outb
            + ((((size_t)b << 18) + ((size_t)(z0 + wv) << 12) + ((y0 + fr) << 6) + x0) << 5)
            + (row << 1);
        #pragma unroll
        for (int qq = 0; qq < 4; ++qq) {
            unsigned pk = cvt_pk_bf16(acc[fr][0][qq], acc[fr][1][qq]);
            *(unsigned*)(ob + ((g4 * 4 + qq) << 5)) = pk;
        }
    }

    __syncthreads();
    if (tid < 64) {
        int n = tid & 31, sel = tid >> 5;
        float tot = 0.f;
        #pragma unroll
        for (int w = 0; w < 8; ++w) tot += s_red[(w * 32 + n) * 2 + sel];
        atomicAdd(&raw_out[(b * 32 + n) * 2 + sel], tot);
    }
}

// ---------------------------------------------------------------------------
// ROI pooling GEMM with fused mask read + fused stats finalization.
// ---------------------------------------------------------------------------
__global__ __launch_bounds__(256)
void pool_mfma_k(const unsigned short* __restrict__ emb, const float* __restrict__ raw3,
                 const float* __restrict__ mask, float* __restrict__ part,
                 float* __restrict__ cntp)
{
    __shared__ unsigned short Ald[64 * 136];
    __shared__ unsigned short Bld[96 * 136];
    __shared__ float s_ns[128];

    const int tid  = threadIdx.x;
    const int lane = tid & 63, wv = tid >> 6;
    const int row  = lane & 15, g4 = lane >> 4;

    if (tid < 64) {
        float sm = raw3[tid * 2], sq = raw3[tid * 2 + 1];
        float mean = sm * (1.f / 262144.f);
        float var  = sq * (1.f / 262144.f) - mean * mean;
        float r = rsqrtf(var + EPS_F);
        s_ns[tid]      = r;
        s_ns[64 + tid] = -mean * r;
    }

    f32x4 acc[6] = {};
    float csum[6] = {};

    for (int ch = 0; ch < 4; ++ch) {
        const int s0 = (blockIdx.x * 4 + ch) << 7;
        __syncthreads();
        for (int i = tid; i < 1024; i += 256) {
            int bb = i >> 9, v = (i >> 2) & 127, g = i & 3;
            u32x4 rv = *(const u32x4*)(emb + (((size_t)bb << 18) + (size_t)(s0 + v)) * 32 + (g << 3));
            #pragma unroll
            for (int k = 0; k < 4; ++k) {
                int bc = bb * 32 + (g << 3) + 2 * k;
                float ve = __builtin_bit_cast(float, rv[k] << 16);
                float vo = __builtin_bit_cast(float, rv[k] & 0xFFFF0000u);
                float ne = fmaxf(0.f, fmaf(ve, s_ns[bc],     s_ns[64 + bc]));
                float no = fmaxf(0.f, fmaf(vo, s_ns[bc + 1], s_ns[64 + bc + 1]));
                unsigned pk = cvt_pk_bf16(ne, no);
                Ald[bc * 136 + v]       = (unsigned short)pk;
                Ald[(bc + 1) * 136 + v] = (unsigned short)(pk >> 16);
            }
        }
        #pragma unroll
        for (int k = 0; k < 6; ++k) {
            int i = tid + k * 256;
            int r = i >> 4, bs = i & 15;
            s16x8 vec = (s16x8)0;
            if (r < 90) {
                const float* mp = mask + (size_t)r * S_TOT + s0 + bs * 8;
                float4 m0 = *(const float4*)mp;
                float4 m1 = *(const float4*)(mp + 4);
                vec[0] = (m0.x != 0.f) ? (short)0x3F80 : (short)0;
                vec[1] = (m0.y != 0.f) ? (short)0x3F80 : (short)0;
                vec[2] = (m0.z != 0.f) ? (short)0x3F80 : (short)0;
                vec[3] = (m0.w != 0.f) ? (short)0x3F80 : (short)0;
                vec[4] = (m1.x != 0.f) ? (short)0x3F80 : (short)0;
                vec[5] = (m1.y != 0.f) ? (short)0x3F80 : (short)0;
                vec[6] = (m1.z != 0.f) ? (short)0x3F80 : (short)0;
                vec[7] = (m1.w != 0.f) ? (short)0x3F80 : (short)0;
                csum[k] += m0.x + m0.y + m0.z + m0.w + m1.x + m1.y + m1.z + m1.w;
            }
            *(s16x8*)&Bld[r * 136 + bs * 8] = vec;
        }
        __syncthreads();
        #pragma unroll
        for (int kk = 0; kk < 4; ++kk) {
            s16x8 a = *(const s16x8*)&Ald[(wv * 16 + row) * 136 + kk * 32 + g4 * 8];
            #pragma unroll
            for (int j = 0; j < 6; ++j) {
                s16x8 bb = *(const s16x8*)&Bld[(j * 16 + row) * 136 + kk * 32 + g4 * 8];
                acc[j] = __builtin_amdgcn_mfma_f32_16x16x32_bf16(a, bb, acc[j], 0, 0, 0);
            }
        }
    }
    #pragma unroll
    for (int k = 0; k < 6; ++k) {
        float c = csum[k];
        c += __shfl_xor(c, 1); c += __shfl_xor(c, 2);
        c += __shfl_xor(c, 4); c += __shfl_xor(c, 8);
        if ((tid & 15) == 0)
            cntp[(size_t)blockIdx.x * 96 + (tid >> 4) + k * 16] = c;
    }
    #pragma unroll
    for (int j = 0; j < 6; ++j) {
        *(f32x4*)&part[((size_t)blockIdx.x * 96 + j * 16 + row) * 64 + wv * 16 + g4 * 4]
            = acc[j];
    }
}

// ---------------------------------------------------------------------------
// Per-ROI partial+count reduction (256-thread wide) + gated MLP + projection.
// ---------------------------------------------------------------------------
__global__ __launch_bounds__(256)
void mlp_k(const float* __restrict__ part, const float* __restrict__ cntp,
           const float* __restrict__ w1, const float* __restrict__ b1,
           const float* __restrict__ w2, const float* __restrict__ b2,
           const float* __restrict__ pw1, const float* __restrict__ pb1,
           const float* __restrict__ pw2, const float* __restrict__ pb2,
           float* __restrict__ out)
{
    const int r   = blockIdx.x % 90;
    const int b   = blockIdx.x / 90;
    const int tid = threadIdx.x;
    __shared__ float sred[8 * 32];
    __shared__ float scnt[4];
    __shared__ float roi_s[32], h_s[64], f_s[32], p_s[64];

    {
        float csp = 0.f;
        for (int p = tid; p < NPART; p += 256) csp += cntp[(size_t)p * 96 + r];
        #pragma unroll
        for (int off = 32; off > 0; off >>= 1) csp += __shfl_xor(csp, off);
        if ((tid & 63) == 0) scnt[tid >> 6] = csp;
    }
    {
        const int c = tid & 31, seg = tid >> 5;
        const float* pp = part + ((size_t)(seg * (NPART / 8)) * 96 + r) * 64 + b * 32 + c;
        float s = 0.f;
        #pragma unroll 4
        for (int p = 0; p < NPART / 8; ++p) s += pp[(size_t)p * 6144];
        sred[seg * 32 + c] = s;
    }
    __syncthreads();
    if (tid < 32) {
        float cs = scnt[0] + scnt[1] + scnt[2] + scnt[3];
        float t = 0.f;
        #pragma unroll
        for (int k = 0; k < 8; ++k) t += sred[k * 32 + tid];
        roi_s[tid] = t / cs;
    }
    __syncthreads();
    if (tid < 64) {
        float s = b1[r * 64 + tid];
        for (int c = 0; c < 32; ++c)
            s = fmaf(roi_s[c], w1[(r * 32 + c) * 64 + tid], s);
        h_s[tid] = fmaxf(s, 0.f);
    }
    __syncthreads();
    if (tid < 32) {
        float s = b2[r * 32 + tid];
        for (int j = 0; j < 64; ++j)
            s = fmaf(h_s[j], w2[(r * 64 + j) * 32 + tid], s);
        float gate = 1.f / (1.f + expf(-s));
        f_s[tid] = gate * roi_s[tid];
    }
    __syncthreads();
    if (tid < 64) {
        float s = pb1[r * 64 + tid];
        for (int c = 0; c < 32; ++c)
            s = fmaf(f_s[c], pw1[(r * 32 + c) * 64 + tid], s);
        p_s[tid] = fmaxf(s, 0.f);
    }
    __syncthreads();
    if (tid < 32) {
        float s = pb2[r * 32 + tid];
        for (int j = 0; j < 64; ++j)
            s = fmaf(p_s[j], pw2[(r * 64 + j) * 32 + tid], s);
        out[((size_t)b * 90 + r) * 32 + tid] = s;
    }
}

// ---------------------------------------------------------------------------
extern "C" void kernel_launch(void* const* d_in, const int* in_sizes, int n_in,
                              void* d_out, int out_size, void* d_ws, size_t ws_size,
                              hipStream_t stream)
{
    const float* data    = (const float*)d_in[0];
    const float* mask    = (const float*)d_in[1];
    const float* conv0_w = (const float*)d_in[2];
    const float* convs_w = (const float*)d_in[4];
    const float* sw1 = (const float*)d_in[6];
    const float* sb1 = (const float*)d_in[7];
    const float* sw2 = (const float*)d_in[8];
    const float* sb2 = (const float*)d_in[9];
    const float* pw1 = (const float*)d_in[10];
    const float* pb1 = (const float*)d_in[11];
    const float* pw2 = (const float*)d_in[12];
    const float* pb2 = (const float*)d_in[13];
    float* out = (float*)d_out;

    float* ws = (float*)d_ws;
    unsigned short* bufA = (unsigned short*)ws;                  // 16,777,216 bf16
    unsigned short* bufB = (unsigned short*)(ws + 8388608);      // 16,777,216 bf16
    unsigned short* wpad = (unsigned short*)(ws + 16777216);     // conv0 weights
    unsigned short* whp  = (unsigned short*)(ws + 16887808);     // packed hi (82,944)
    float* raw   = ws + 16929280;        // 512 (4 layers x 128)
    float* part  = ws + 17825792;        // NPART*96*64 floats
    float* cntp  = part + 3145728;       // NPART*96 floats

    hipMemsetAsync(raw, 0, 512 * sizeof(float), stream);
    prep_w_k<<<332, 256, 0, stream>>>(conv0_w, convs_w, wpad, whp);

    // layer 0: data(fp32) -> bufA, raw sums -> raw[0..127]
    conv0_k<<<512, 512, 0, stream>>>(data, wpad, bufA, raw);
    // layer 1: bufA -> bufB (stats fused from raw)
    conv_slab_k<<<1024, 512, 0, stream>>>(bufA, whp, raw, bufB, raw + 128);
    // layer 2: bufB -> bufA
    conv_slab_k<<<1024, 512, 0, stream>>>(bufB, whp + 27648, raw + 128, bufA, raw + 256);
    // layer 3: bufA -> bufB
    conv_slab_k<<<1024, 512, 0, stream>>>(bufA, whp + 2 * 27648, raw + 256, bufB, raw + 384);

    // ROI pooling GEMM (stats fused from raw+384) -> partials + counts
    pool_mfma_k<<<NPART, 256, 0, stream>>>(bufB, raw + 384, mask, part, cntp);

    // per-ROI partial reduction + MLPs
    mlp_k<<<180, 256, 0, stream>>>(part, cntp, sw1, sb1, sw2, sb2,
                                   pw1, pb1, pw2, pb2, out);
}

// Round 18
// 214.807 us; speedup vs baseline: 1.1193x; 1.1193x over previous
//
#include <hip/hip_runtime.h>
#include <hip/hip_bf16.h>
#include <math.h>

#define S_TOT 262144   // 64^3
#define EPS_F 1e-5f
#define NPART 512      // pool partial-K blocks
#define PLSTR 14416    // LDS plane stride in shorts (28832B ≡ 32B mod 128)

typedef __attribute__((ext_vector_type(8))) short s16x8;
typedef __attribute__((ext_vector_type(4))) float f32x4;
typedef __attribute__((ext_vector_type(4))) unsigned u32x4;

__device__ __forceinline__ unsigned short f2bf(float f) {   // RNE, manual (prep only)
    unsigned u = __builtin_bit_cast(unsigned, f);
    unsigned r = (u + 0x7FFFu + ((u >> 16) & 1u)) >> 16;
    return (unsigned short)r;
}
__device__ __forceinline__ float bf2f(unsigned short u) {
    return __builtin_bit_cast(float, ((unsigned)u) << 16);
}
// HW packed convert: low16 = bf16(a), high16 = bf16(b), RNE.
__device__ __forceinline__ unsigned cvt_pk_bf16(float a, float b) {
    unsigned r;
    asm("v_cvt_pk_bf16_f32 %0, %1, %2" : "=v"(r) : "v"(a), "v"(b));
    return r;
}

// ---------------------------------------------------------------------------
// Weight prep.
// Layer 0: w0[hi|lo][brow][k=tap(32,pad0)] at wpad[0..2047]  (hi+lo used).
// Layers 1-3: PACKED hi-only at whp[(layer-1)*27648 + tap*1024 + brow*32 + cin].
// brow(cout) = ((cout&1)<<4) | (cout>>1).
// ---------------------------------------------------------------------------
__global__ __launch_bounds__(256)
void prep_w_k(const float* __restrict__ conv0_w, const float* __restrict__ convs_w,
              unsigned short* __restrict__ wpad, unsigned short* __restrict__ whp)
{
    int idx = blockIdx.x * 256 + threadIdx.x;
    if (idx < 2048) {
        int brow = idx >> 5, k = idx & 31;
        int cout = 2 * (brow & 15) + (brow >> 4);
        float wv = (k < 27) ? conv0_w[cout * 27 + k] : 0.f;
        unsigned short hi = f2bf(wv);
        unsigned short lo = f2bf(wv - bf2f(hi));
        wpad[brow * 32 + k]        = hi;
        wpad[1024 + brow * 32 + k] = lo;
        return;
    }
    int j = idx - 2048;
    if (j >= 3 * 27648) return;
    int layer = j / 27648 + 1;
    int rem   = j % 27648;
    int tap   = rem >> 10;
    int cout  = (rem >> 5) & 31;
    int cin   = rem & 31;
    float wv = convs_w[(((layer - 1) * 32 + cout) * 32 + cin) * 27 + tap];
    unsigned short hi = f2bf(wv);
    int brow = ((cout & 1) << 4) | (cout >> 1);
    whp[(size_t)(layer - 1) * 27648 + tap * 1024 + brow * 32 + cin] = hi;
}

// ---------------------------------------------------------------------------
// Layer 0: cin=1 im2col over taps (K = 27 taps padded to 32), hi+lo.
// 512 blocks (8x8x16 slab), 512 threads, wave wv owns z-planes {2wv,2wv+1}.
// ---------------------------------------------------------------------------
__global__ __launch_bounds__(512, 2)
void conv0_k(const float* __restrict__ in, const unsigned short* __restrict__ w0,
             unsigned short* __restrict__ outb, float* __restrict__ raw_out)
{
    __shared__ unsigned short sc[1824];
    __shared__ float s_red[512];

    const int tid  = threadIdx.x;
    const int lane = tid & 63;
    const int wv   = tid >> 6;
    const int row  = lane & 15;
    const int g4   = lane >> 4;

    const int blk = blockIdx.x;
    const int b   = blk >> 8;
    const int t   = blk & 255;
    const int x0  = (t & 7) << 3;
    const int y0  = ((t >> 3) & 7) << 3;
    const int z0  = (t >> 6) << 4;

    for (int i = tid; i < 1800; i += 512) {
        int zz = i / 100, r2 = i - zz * 100, yy = r2 / 10, xx = r2 - yy * 10;
        int gz = z0 + zz - 1, gy = y0 + yy - 1, gx = x0 + xx - 1;
        float v = 0.f;
        if ((unsigned)gz < 64u && (unsigned)gy < 64u && (unsigned)gx < 64u)
            v = in[((size_t)b << 18) + (gz << 12) + (gy << 6) + gx];
        sc[i] = (unsigned short)cvt_pk_bf16(v, v);
    }
    __syncthreads();

    int dvox[8];
    #pragma unroll
    for (int j = 0; j < 8; ++j) {
        int tap = g4 * 8 + j;
        if (tap < 27) {
            int dz = tap / 9, r9 = tap - dz * 9, dy = r9 / 3, dx = r9 - dy * 3;
            dvox[j] = dz * 100 + dy * 10 + dx;
        } else dvox[j] = 0;
    }

    s16x8 wh0 = *(const s16x8*)(w0 + row * 32 + g4 * 8);
    s16x8 wh1 = *(const s16x8*)(w0 + (16 + row) * 32 + g4 * 8);
    s16x8 wl0 = *(const s16x8*)(w0 + 1024 + row * 32 + g4 * 8);
    s16x8 wl1 = *(const s16x8*)(w0 + 1024 + (16 + row) * 32 + g4 * 8);

    f32x4 acc[2][4][2] = {};
    #pragma unroll
    for (int pl = 0; pl < 2; ++pl) {
        #pragma unroll
        for (int f = 0; f < 4; ++f) {
            int vvx = f * 16 + row;
            int base = (2 * wv + pl) * 100 + (vvx >> 3) * 10 + (vvx & 7);
            s16x8 a;
            #pragma unroll
            for (int j = 0; j < 8; ++j) a[j] = (short)sc[base + dvox[j]];
            acc[pl][f][0] = __builtin_amdgcn_mfma_f32_16x16x32_bf16(a, wh0, acc[pl][f][0], 0, 0, 0);
            acc[pl][f][0] = __builtin_amdgcn_mfma_f32_16x16x32_bf16(a, wl0, acc[pl][f][0], 0, 0, 0);
            acc[pl][f][1] = __builtin_amdgcn_mfma_f32_16x16x32_bf16(a, wh1, acc[pl][f][1], 0, 0, 0);
            acc[pl][f][1] = __builtin_amdgcn_mfma_f32_16x16x32_bf16(a, wl1, acc[pl][f][1], 0, 0, 0);
        }
    }

    {
        float s0 = 0.f, ss0 = 0.f, s1 = 0.f, ss1 = 0.f;
        #pragma unroll
        for (int pl = 0; pl < 2; ++pl)
            #pragma unroll
            for (int f = 0; f < 4; ++f)
                #pragma unroll
                for (int q = 0; q < 4; ++q) {
                    float v0 = acc[pl][f][0][q], v1 = acc[pl][f][1][q];
                    s0 += v0; ss0 += v0 * v0; s1 += v1; ss1 += v1 * v1;
                }
        s0 += __shfl_xor(s0, 16); s0 += __shfl_xor(s0, 32);
        ss0 += __shfl_xor(ss0, 16); ss0 += __shfl_xor(ss0, 32);
        s1 += __shfl_xor(s1, 16); s1 += __shfl_xor(s1, 32);
        ss1 += __shfl_xor(ss1, 16); ss1 += __shfl_xor(ss1, 32);
        if (lane < 16) {
            s_red[(wv * 32 + 2 * row) * 2]         = s0;
            s_red[(wv * 32 + 2 * row) * 2 + 1]     = ss0;
            s_red[(wv * 32 + 2 * row + 1) * 2]     = s1;
            s_red[(wv * 32 + 2 * row + 1) * 2 + 1] = ss1;
        }
    }

    #pragma unroll
    for (int pl = 0; pl < 2; ++pl) {
        int zp = 2 * wv + pl;
        unsigned short* ob = outb
            + ((((size_t)b << 18) + ((size_t)(z0 + zp) << 12) + (y0 << 6) + x0) << 5)
            + (row << 1);
        #pragma unroll
        for (int f = 0; f < 4; ++f) {
            #pragma unroll
            for (int qq = 0; qq < 4; ++qq) {
                int u = g4 * 4 + qq;
                int yy = f * 2 + (u >> 3), xx = u & 7;
                unsigned pk = cvt_pk_bf16(acc[pl][f][0][qq], acc[pl][f][1][qq]);
                *(unsigned*)(ob + ((yy << 6) + xx) * 32) = pk;
            }
        }
    }

    __syncthreads();
    if (tid < 64) {
        int n = tid & 31, sel = tid >> 5;
        float tot = 0.f;
        #pragma unroll
        for (int w = 0; w < 8; ++w) tot += s_red[(w * 32 + n) * 2 + sel];
        atomicAdd(&raw_out[(b * 32 + n) * 2 + sel], tot);
    }
}

// ---------------------------------------------------------------------------
// Mid conv layers: 16x8x8 X-WIDE tile (halo 18x10x10 = 1800 vox, 115KB LDS),
// 1024 threads = 16 WAVES (4 waves/SIMD from one block -> barrier-free tap
// loop interleaves ds_read latency with MFMA across waves).  Wave w owns
// (z = w>>1, y-half = (w&1)*4), 4 frags each (frag = y-row of 16 consecutive
// x-voxels -> every A ds_read_b128 16-lane phase is one contiguous 256B run).
// HI-ONLY packed weights + prefetch; stats fused; cvt_pk converts.
// ---------------------------------------------------------------------------
__global__ __launch_bounds__(1024, 4)
void conv_slab_k(const unsigned short* __restrict__ in, const unsigned short* __restrict__ whp_l,
                 const float* __restrict__ raw_in, unsigned short* __restrict__ outb,
                 float* __restrict__ raw_out)
{
    __shared__ unsigned short tile[4 * PLSTR];   // 115,328 B
    __shared__ float s_red[1024];

    const int tid  = threadIdx.x;
    const int lane = tid & 63;
    const int wv   = tid >> 6;        // wave 0..15
    const int zz   = wv >> 1;         // z-plane 0..7
    const int yh   = (wv & 1) << 2;   // y-half 0 or 4
    const int row  = lane & 15;       // A: x within frag
    const int g4   = lane >> 4;       // k-chunk
    const int g    = tid & 3;
    const int vox0 = tid >> 2;        // 0..255

    const int blk = blockIdx.x;
    const int b   = blk >> 8;
    const int t   = blk & 255;
    const int x0  = (t & 3) << 4;     // 4 x-tiles of 16
    const int y0  = ((t >> 2) & 7) << 3;
    const int z0  = (t >> 5) << 3;

    // ---- stage halo 18x10x10 (norm+relu fused, cvt_pk) ----
    {
        float rs[8], sh[8];
        #pragma unroll
        for (int j = 0; j < 8; ++j) {
            int c = b * 32 + g * 8 + j;
            float sm = raw_in[c * 2], sq = raw_in[c * 2 + 1];
            float mean = sm * (1.f / 262144.f);
            float var  = sq * (1.f / 262144.f) - mean * mean;
            float r = rsqrtf(var + EPS_F);
            rs[j] = r; sh[j] = -mean * r;
        }
        #pragma unroll 1
        for (int u = 0; u < 8; ++u) {
            int vox = vox0 + u * 256;
            if (vox >= 1800) break;
            int zp = vox / 180, r2 = vox - zp * 180, yy = r2 / 18, xx = r2 - yy * 18;
            int gz = z0 + zp - 1, gy = y0 + yy - 1, gx = x0 + xx - 1;
            u32x4 w = (u32x4)0;
            if ((unsigned)gz < 64u && (unsigned)gy < 64u && (unsigned)gx < 64u) {
                u32x4 rv = *(const u32x4*)(in
                    + ((((size_t)b << 18) + (gz << 12) + (gy << 6) + gx) << 5) + (g << 3));
                #pragma unroll
                for (int k = 0; k < 4; ++k) {
                    float ve = __builtin_bit_cast(float, rv[k] << 16);
                    float vo = __builtin_bit_cast(float, rv[k] & 0xFFFF0000u);
                    float ne = fmaxf(0.f, fmaf(ve, rs[2 * k],     sh[2 * k]));
                    float no = fmaxf(0.f, fmaf(vo, rs[2 * k + 1], sh[2 * k + 1]));
                    w[k] = cvt_pk_bf16(ne, no);
                }
            }
            *(u32x4*)&tile[g * PLSTR + (vox << 3)] = w;
        }
    }
    __syncthreads();

    // ---- MFMA: 27 taps x 4 frags; A reads contiguous 256B per 16-lane phase
    f32x4 acc[4][2] = {};
    {
        const unsigned short* aplane = &tile[g4 * PLSTR];
        int abase[4];
        #pragma unroll
        for (int fr = 0; fr < 4; ++fr)
            abase[fr] = ((zz * 180 + (yh + fr) * 18 + row) << 3);
        const unsigned short* wrow = whp_l + row * 32 + g4 * 8;

        s16x8 wh0 = *(const s16x8*)(wrow);
        s16x8 wh1 = *(const s16x8*)(wrow + 512);

        #pragma unroll 1
        for (int tap = 0; tap < 27; ++tap) {
            int ntap = (tap < 26) ? tap + 1 : 26;
            const unsigned short* wn = wrow + ntap * 1024;
            s16x8 nh0 = *(const s16x8*)(wn);
            s16x8 nh1 = *(const s16x8*)(wn + 512);

            int dz = tap / 9, r9 = tap - dz * 9, dy = r9 / 3, dx = r9 - dy * 3;
            int doff = ((dz * 180 + dy * 18 + dx) << 3);
            #pragma unroll
            for (int fr = 0; fr < 4; ++fr) {
                s16x8 a = *(const s16x8*)&aplane[abase[fr] + doff];
                acc[fr][0] = __builtin_amdgcn_mfma_f32_16x16x32_bf16(a, wh0, acc[fr][0], 0, 0, 0);
                acc[fr][1] = __builtin_amdgcn_mfma_f32_16x16x32_bf16(a, wh1, acc[fr][1], 0, 0, 0);
            }
            wh0 = nh0; wh1 = nh1;
        }
    }

    // ---- instance-norm partial stats ----
    {
        float s0 = 0.f, ss0 = 0.f, s1 = 0.f, ss1 = 0.f;
        #pragma unroll
        for (int fr = 0; fr < 4; ++fr)
            #pragma unroll
            for (int q = 0; q < 4; ++q) {
                float v0 = acc[fr][0][q], v1 = acc[fr][1][q];
                s0 += v0; ss0 += v0 * v0; s1 += v1; ss1 += v1 * v1;
            }
        s0 += __shfl_xor(s0, 16); s0 += __shfl_xor(s0, 32);
        ss0 += __shfl_xor(ss0, 16); ss0 += __shfl_xor(ss0, 32);
        s1 += __shfl_xor(s1, 16); s1 += __shfl_xor(s1, 32);
        ss1 += __shfl_xor(ss1, 16); ss1 += __shfl_xor(ss1, 32);
        if (lane < 16) {
            s_red[(wv * 32 + 2 * row) * 2]         = s0;
            s_red[(wv * 32 + 2 * row) * 2 + 1]     = ss0;
            s_red[(wv * 32 + 2 * row + 1) * 2]     = s1;
            s_red[(wv * 32 + 2 * row + 1) * 2 + 1] = ss1;
        }
    }

    // ---- packed channel-pair stores: voxel x = g4*4+qq, y = yh+fr, z = zz --
    #pragma unroll
    for (int fr = 0; fr < 4; ++fr) {
        unsigned short* ob = outb
            + ((((size_t)b << 18) + ((size_t)(z0 + zz) << 12) + ((y0 + yh + fr) << 6) + x0) << 5)
            + (row << 1);
        #pragma unroll
        for (int qq = 0; qq < 4; ++qq) {
            unsigned pk = cvt_pk_bf16(acc[fr][0][qq], acc[fr][1][qq]);
            *(unsigned*)(ob + ((g4 * 4 + qq) << 5)) = pk;
        }
    }

    __syncthreads();
    if (tid < 64) {
        int n = tid & 31, sel = tid >> 5;
        float tot = 0.f;
        #pragma unroll
        for (int w = 0; w < 16; ++w) tot += s_red[(w * 32 + n) * 2 + sel];
        atomicAdd(&raw_out[(b * 32 + n) * 2 + sel], tot);
    }
}

// ---------------------------------------------------------------------------
// ROI pooling GEMM with fused mask read + fused stats finalization.
// ---------------------------------------------------------------------------
__global__ __launch_bounds__(256)
void pool_mfma_k(const unsigned short* __restrict__ emb, const float* __restrict__ raw3,
                 const float* __restrict__ mask, float* __restrict__ part,
                 float* __restrict__ cntp)
{
    __shared__ unsigned short Ald[64 * 136];
    __shared__ unsigned short Bld[96 * 136];
    __shared__ float s_ns[128];

    const int tid  = threadIdx.x;
    const int lane = tid & 63, wv = tid >> 6;
    const int row  = lane & 15, g4 = lane >> 4;

    if (tid < 64) {
        float sm = raw3[tid * 2], sq = raw3[tid * 2 + 1];
        float mean = sm * (1.f / 262144.f);
        float var  = sq * (1.f / 262144.f) - mean * mean;
        float r = rsqrtf(var + EPS_F);
        s_ns[tid]      = r;
        s_ns[64 + tid] = -mean * r;
    }

    f32x4 acc[6] = {};
    float csum[6] = {};

    for (int ch = 0; ch < 4; ++ch) {
        const int s0 = (blockIdx.x * 4 + ch) << 7;
        __syncthreads();
        for (int i = tid; i < 1024; i += 256) {
            int bb = i >> 9, v = (i >> 2) & 127, g = i & 3;
            u32x4 rv = *(const u32x4*)(emb + (((size_t)bb << 18) + (size_t)(s0 + v)) * 32 + (g << 3));
            #pragma unroll
            for (int k = 0; k < 4; ++k) {
                int bc = bb * 32 + (g << 3) + 2 * k;
                float ve = __builtin_bit_cast(float, rv[k] << 16);
                float vo = __builtin_bit_cast(float, rv[k] & 0xFFFF0000u);
                float ne = fmaxf(0.f, fmaf(ve, s_ns[bc],     s_ns[64 + bc]));
                float no = fmaxf(0.f, fmaf(vo, s_ns[bc + 1], s_ns[64 + bc + 1]));
                unsigned pk = cvt_pk_bf16(ne, no);
                Ald[bc * 136 + v]       = (unsigned short)pk;
                Ald[(bc + 1) * 136 + v] = (unsigned short)(pk >> 16);
            }
        }
        #pragma unroll
        for (int k = 0; k < 6; ++k) {
            int i = tid + k * 256;
            int r = i >> 4, bs = i & 15;
            s16x8 vec = (s16x8)0;
            if (r < 90) {
                const float* mp = mask + (size_t)r * S_TOT + s0 + bs * 8;
                float4 m0 = *(const float4*)mp;
                float4 m1 = *(const float4*)(mp + 4);
                vec[0] = (m0.x != 0.f) ? (short)0x3F80 : (short)0;
                vec[1] = (m0.y != 0.f) ? (short)0x3F80 : (short)0;
                vec[2] = (m0.z != 0.f) ? (short)0x3F80 : (short)0;
                vec[3] = (m0.w != 0.f) ? (short)0x3F80 : (short)0;
                vec[4] = (m1.x != 0.f) ? (short)0x3F80 : (short)0;
                vec[5] = (m1.y != 0.f) ? (short)0x3F80 : (short)0;
                vec[6] = (m1.z != 0.f) ? (short)0x3F80 : (short)0;
                vec[7] = (m1.w != 0.f) ? (short)0x3F80 : (short)0;
                csum[k] += m0.x + m0.y + m0.z + m0.w + m1.x + m1.y + m1.z + m1.w;
            }
            *(s16x8*)&Bld[r * 136 + bs * 8] = vec;
        }
        __syncthreads();
        #pragma unroll
        for (int kk = 0; kk < 4; ++kk) {
            s16x8 a = *(const s16x8*)&Ald[(wv * 16 + row) * 136 + kk * 32 + g4 * 8];
            #pragma unroll
            for (int j = 0; j < 6; ++j) {
                s16x8 bb = *(const s16x8*)&Bld[(j * 16 + row) * 136 + kk * 32 + g4 * 8];
                acc[j] = __builtin_amdgcn_mfma_f32_16x16x32_bf16(a, bb, acc[j], 0, 0, 0);
            }
        }
    }
    #pragma unroll
    for (int k = 0; k < 6; ++k) {
        float c = csum[k];
        c += __shfl_xor(c, 1); c += __shfl_xor(c, 2);
        c += __shfl_xor(c, 4); c += __shfl_xor(c, 8);
        if ((tid & 15) == 0)
            cntp[(size_t)blockIdx.x * 96 + (tid >> 4) + k * 16] = c;
    }
    #pragma unroll
    for (int j = 0; j < 6; ++j) {
        *(f32x4*)&part[((size_t)blockIdx.x * 96 + j * 16 + row) * 64 + wv * 16 + g4 * 4]
            = acc[j];
    }
}

// ---------------------------------------------------------------------------
// Per-ROI partial+count reduction (256-thread wide) + gated MLP + projection.
// ---------------------------------------------------------------------------
__global__ __launch_bounds__(256)
void mlp_k(const float* __restrict__ part, const float* __restrict__ cntp,
           const float* __restrict__ w1, const float* __restrict__ b1,
           const float* __restrict__ w2, const float* __restrict__ b2,
           const float* __restrict__ pw1, const float* __restrict__ pb1,
           const float* __restrict__ pw2, const float* __restrict__ pb2,
           float* __restrict__ out)
{
    const int r   = blockIdx.x % 90;
    const int b   = blockIdx.x / 90;
    const int tid = threadIdx.x;
    __shared__ float sred[8 * 32];
    __shared__ float scnt[4];
    __shared__ float roi_s[32], h_s[64], f_s[32], p_s[64];

    {
        float csp = 0.f;
        for (int p = tid; p < NPART; p += 256) csp += cntp[(size_t)p * 96 + r];
        #pragma unroll
        for (int off = 32; off > 0; off >>= 1) csp += __shfl_xor(csp, off);
        if ((tid & 63) == 0) scnt[tid >> 6] = csp;
    }
    {
        const int c = tid & 31, seg = tid >> 5;
        const float* pp = part + ((size_t)(seg * (NPART / 8)) * 96 + r) * 64 + b * 32 + c;
        float s = 0.f;
        #pragma unroll 4
        for (int p = 0; p < NPART / 8; ++p) s += pp[(size_t)p * 6144];
        sred[seg * 32 + c] = s;
    }
    __syncthreads();
    if (tid < 32) {
        float cs = scnt[0] + scnt[1] + scnt[2] + scnt[3];
        float t = 0.f;
        #pragma unroll
        for (int k = 0; k < 8; ++k) t += sred[k * 32 + tid];
        roi_s[tid] = t / cs;
    }
    __syncthreads();
    if (tid < 64) {
        float s = b1[r * 64 + tid];
        for (int c = 0; c < 32; ++c)
            s = fmaf(roi_s[c], w1[(r * 32 + c) * 64 + tid], s);
        h_s[tid] = fmaxf(s, 0.f);
    }
    __syncthreads();
    if (tid < 32) {
        float s = b2[r * 32 + tid];
        for (int j = 0; j < 64; ++j)
            s = fmaf(h_s[j], w2[(r * 64 + j) * 32 + tid], s);
        float gate = 1.f / (1.f + expf(-s));
        f_s[tid] = gate * roi_s[tid];
    }
    __syncthreads();
    if (tid < 64) {
        float s = pb1[r * 64 + tid];
        for (int c = 0; c < 32; ++c)
            s = fmaf(f_s[c], pw1[(r * 32 + c) * 64 + tid], s);
        p_s[tid] = fmaxf(s, 0.f);
    }
    __syncthreads();
    if (tid < 32) {
        float s = pb2[r * 32 + tid];
        for (int j = 0; j < 64; ++j)
            s = fmaf(p_s[j], pw2[(r * 64 + j) * 32 + tid], s);
        out[((size_t)b * 90 + r) * 32 + tid] = s;
    }
}

// ---------------------------------------------------------------------------
extern "C" void kernel_launch(void* const* d_in, const int* in_sizes, int n_in,
                              void* d_out, int out_size, void* d_ws, size_t ws_size,
                              hipStream_t stream)
{
    const float* data    = (const float*)d_in[0];
    const float* mask    = (const float*)d_in[1];
    const float* conv0_w = (const float*)d_in[2];
    const float* convs_w = (const float*)d_in[4];
    const float* sw1 = (const float*)d_in[6];
    const float* sb1 = (const float*)d_in[7];
    const float* sw2 = (const float*)d_in[8];
    const float* sb2 = (const float*)d_in[9];
    const float* pw1 = (const float*)d_in[10];
    const float* pb1 = (const float*)d_in[11];
    const float* pw2 = (const float*)d_in[12];
    const float* pb2 = (const float*)d_in[13];
    float* out = (float*)d_out;

    float* ws = (float*)d_ws;
    unsigned short* bufA = (unsigned short*)ws;                  // 16,777,216 bf16
    unsigned short* bufB = (unsigned short*)(ws + 8388608);      // 16,777,216 bf16
    unsigned short* wpad = (unsigned short*)(ws + 16777216);     // conv0 weights
    unsigned short* whp  = (unsigned short*)(ws + 16887808);     // packed hi (82,944)
    float* raw   = ws + 16929280;        // 512 (4 layers x 128)
    float* part  = ws + 17825792;        // NPART*96*64 floats
    float* cntp  = part + 3145728;       // NPART*96 floats

    hipMemsetAsync(raw, 0, 512 * sizeof(float), stream);
    prep_w_k<<<332, 256, 0, stream>>>(conv0_w, convs_w, wpad, whp);

    // layer 0: data(fp32) -> bufA, raw sums -> raw[0..127]
    conv0_k<<<512, 512, 0, stream>>>(data, wpad, bufA, raw);
    // layer 1: bufA -> bufB (stats fused from raw)
    conv_slab_k<<<512, 1024, 0, stream>>>(bufA, whp, raw, bufB, raw + 128);
    // layer 2: bufB -> bufA
    conv_slab_k<<<512, 1024, 0, stream>>>(bufB, whp + 27648, raw + 128, bufA, raw + 256);
    // layer 3: bufA -> bufB
    conv_slab_k<<<512, 1024, 0, stream>>>(bufA, whp + 2 * 27648, raw + 256, bufB, raw + 384);

    // ROI pooling GEMM (stats fused from raw+384) -> partials + counts
    pool_mfma_k<<<NPART, 256, 0, stream>>>(bufB, raw + 384, mask, part, cntp);

    // per-ROI partial reduction + MLPs
    mlp_k<<<180, 256, 0, stream>>>(part, cntp, sw1, sb1, sw2, sb2,
                                   pw1, pb1, pw2, pb2, out);
}

// Round 19
// 214.400 us; speedup vs baseline: 1.1215x; 1.0019x over previous
//
#include <hip/hip_runtime.h>
#include <hip/hip_bf16.h>
#include <math.h>

#define S_TOT 262144   // 64^3
#define EPS_F 1e-5f
#define NPART 512      // pool partial-K blocks
#define PLSTR 14416    // LDS plane stride in shorts (28832B ≡ 32B mod 128)

typedef __attribute__((ext_vector_type(8))) short s16x8;
typedef __attribute__((ext_vector_type(4))) float f32x4;
typedef __attribute__((ext_vector_type(4))) unsigned u32x4;

__device__ __forceinline__ unsigned short f2bf(float f) {   // RNE, manual (prep only)
    unsigned u = __builtin_bit_cast(unsigned, f);
    unsigned r = (u + 0x7FFFu + ((u >> 16) & 1u)) >> 16;
    return (unsigned short)r;
}
__device__ __forceinline__ float bf2f(unsigned short u) {
    return __builtin_bit_cast(float, ((unsigned)u) << 16);
}
// HW packed convert: low16 = bf16(a), high16 = bf16(b), RNE.
__device__ __forceinline__ unsigned cvt_pk_bf16(float a, float b) {
    unsigned r;
    asm("v_cvt_pk_bf16_f32 %0, %1, %2" : "=v"(r) : "v"(a), "v"(b));
    return r;
}

// ---------------------------------------------------------------------------
// Weight prep.
// Layer 0: w0[hi|lo][brow][k=tap(32,pad0)] at wpad[0..2047]  (hi+lo used).
// Layers 1-3: PACKED hi-only at whp[(layer-1)*27648 + tap*1024 + brow*32 + cin].
// brow(cout) = ((cout&1)<<4) | (cout>>1).
// ---------------------------------------------------------------------------
__global__ __launch_bounds__(256)
void prep_w_k(const float* __restrict__ conv0_w, const float* __restrict__ convs_w,
              unsigned short* __restrict__ wpad, unsigned short* __restrict__ whp)
{
    int idx = blockIdx.x * 256 + threadIdx.x;
    if (idx < 2048) {
        int brow = idx >> 5, k = idx & 31;
        int cout = 2 * (brow & 15) + (brow >> 4);
        float wv = (k < 27) ? conv0_w[cout * 27 + k] : 0.f;
        unsigned short hi = f2bf(wv);
        unsigned short lo = f2bf(wv - bf2f(hi));
        wpad[brow * 32 + k]        = hi;
        wpad[1024 + brow * 32 + k] = lo;
        return;
    }
    int j = idx - 2048;
    if (j >= 3 * 27648) return;
    int layer = j / 27648 + 1;
    int rem   = j % 27648;
    int tap   = rem >> 10;
    int cout  = (rem >> 5) & 31;
    int cin   = rem & 31;
    float wv = convs_w[(((layer - 1) * 32 + cout) * 32 + cin) * 27 + tap];
    unsigned short hi = f2bf(wv);
    int brow = ((cout & 1) << 4) | (cout >> 1);
    whp[(size_t)(layer - 1) * 27648 + tap * 1024 + brow * 32 + cin] = hi;
}

// ---------------------------------------------------------------------------
// Layer 0: cin=1 im2col over taps (K = 27 taps padded to 32), hi+lo.
// 512 blocks (8x8x16 slab), 512 threads, wave wv owns z-planes {2wv,2wv+1}.
// ---------------------------------------------------------------------------
__global__ __launch_bounds__(512, 2)
void conv0_k(const float* __restrict__ in, const unsigned short* __restrict__ w0,
             unsigned short* __restrict__ outb, float* __restrict__ raw_out)
{
    __shared__ unsigned short sc[1824];
    __shared__ float s_red[512];

    const int tid  = threadIdx.x;
    const int lane = tid & 63;
    const int wv   = tid >> 6;
    const int row  = lane & 15;
    const int g4   = lane >> 4;

    const int blk = blockIdx.x;
    const int b   = blk >> 8;
    const int t   = blk & 255;
    const int x0  = (t & 7) << 3;
    const int y0  = ((t >> 3) & 7) << 3;
    const int z0  = (t >> 6) << 4;

    for (int i = tid; i < 1800; i += 512) {
        int zz = i / 100, r2 = i - zz * 100, yy = r2 / 10, xx = r2 - yy * 10;
        int gz = z0 + zz - 1, gy = y0 + yy - 1, gx = x0 + xx - 1;
        float v = 0.f;
        if ((unsigned)gz < 64u && (unsigned)gy < 64u && (unsigned)gx < 64u)
            v = in[((size_t)b << 18) + (gz << 12) + (gy << 6) + gx];
        sc[i] = (unsigned short)cvt_pk_bf16(v, v);
    }
    __syncthreads();

    int dvox[8];
    #pragma unroll
    for (int j = 0; j < 8; ++j) {
        int tap = g4 * 8 + j;
        if (tap < 27) {
            int dz = tap / 9, r9 = tap - dz * 9, dy = r9 / 3, dx = r9 - dy * 3;
            dvox[j] = dz * 100 + dy * 10 + dx;
        } else dvox[j] = 0;
    }

    s16x8 wh0 = *(const s16x8*)(w0 + row * 32 + g4 * 8);
    s16x8 wh1 = *(const s16x8*)(w0 + (16 + row) * 32 + g4 * 8);
    s16x8 wl0 = *(const s16x8*)(w0 + 1024 + row * 32 + g4 * 8);
    s16x8 wl1 = *(const s16x8*)(w0 + 1024 + (16 + row) * 32 + g4 * 8);

    f32x4 acc[2][4][2] = {};
    #pragma unroll
    for (int pl = 0; pl < 2; ++pl) {
        #pragma unroll
        for (int f = 0; f < 4; ++f) {
            int vvx = f * 16 + row;
            int base = (2 * wv + pl) * 100 + (vvx >> 3) * 10 + (vvx & 7);
            s16x8 a;
            #pragma unroll
            for (int j = 0; j < 8; ++j) a[j] = (short)sc[base + dvox[j]];
            acc[pl][f][0] = __builtin_amdgcn_mfma_f32_16x16x32_bf16(a, wh0, acc[pl][f][0], 0, 0, 0);
            acc[pl][f][0] = __builtin_amdgcn_mfma_f32_16x16x32_bf16(a, wl0, acc[pl][f][0], 0, 0, 0);
            acc[pl][f][1] = __builtin_amdgcn_mfma_f32_16x16x32_bf16(a, wh1, acc[pl][f][1], 0, 0, 0);
            acc[pl][f][1] = __builtin_amdgcn_mfma_f32_16x16x32_bf16(a, wl1, acc[pl][f][1], 0, 0, 0);
        }
    }

    {
        float s0 = 0.f, ss0 = 0.f, s1 = 0.f, ss1 = 0.f;
        #pragma unroll
        for (int pl = 0; pl < 2; ++pl)
            #pragma unroll
            for (int f = 0; f < 4; ++f)
                #pragma unroll
                for (int q = 0; q < 4; ++q) {
                    float v0 = acc[pl][f][0][q], v1 = acc[pl][f][1][q];
                    s0 += v0; ss0 += v0 * v0; s1 += v1; ss1 += v1 * v1;
                }
        s0 += __shfl_xor(s0, 16); s0 += __shfl_xor(s0, 32);
        ss0 += __shfl_xor(ss0, 16); ss0 += __shfl_xor(ss0, 32);
        s1 += __shfl_xor(s1, 16); s1 += __shfl_xor(s1, 32);
        ss1 += __shfl_xor(ss1, 16); ss1 += __shfl_xor(ss1, 32);
        if (lane < 16) {
            s_red[(wv * 32 + 2 * row) * 2]         = s0;
            s_red[(wv * 32 + 2 * row) * 2 + 1]     = ss0;
            s_red[(wv * 32 + 2 * row + 1) * 2]     = s1;
            s_red[(wv * 32 + 2 * row + 1) * 2 + 1] = ss1;
        }
    }

    #pragma unroll
    for (int pl = 0; pl < 2; ++pl) {
        int zp = 2 * wv + pl;
        unsigned short* ob = outb
            + ((((size_t)b << 18) + ((size_t)(z0 + zp) << 12) + (y0 << 6) + x0) << 5)
            + (row << 1);
        #pragma unroll
        for (int f = 0; f < 4; ++f) {
            #pragma unroll
            for (int qq = 0; qq < 4; ++qq) {
                int u = g4 * 4 + qq;
                int yy = f * 2 + (u >> 3), xx = u & 7;
                unsigned pk = cvt_pk_bf16(acc[pl][f][0][qq], acc[pl][f][1][qq]);
                *(unsigned*)(ob + ((yy << 6) + xx) * 32) = pk;
            }
        }
    }

    __syncthreads();
    if (tid < 64) {
        int n = tid & 31, sel = tid >> 5;
        float tot = 0.f;
        #pragma unroll
        for (int w = 0; w < 8; ++w) tot += s_red[(w * 32 + n) * 2 + sel];
        atomicAdd(&raw_out[(b * 32 + n) * 2 + sel], tot);
    }
}

// ---------------------------------------------------------------------------
// Mid conv layers: 16x8x8 X-WIDE tile, 1024 threads = 16 waves (4/SIMD from
// one block; barrier-free tap loop -> waves drift and interleave ds_read
// latency with MFMA).  Tap loop: INCREMENTAL doff (SALU, no divides) and
// s_setprio(1) around the MFMA cluster (runtime wave arbitration; waves have
// role diversity since they're out of phase).  Frag row = 16 consecutive
// x-voxels -> conflict-free contiguous 256B A reads.
// ---------------------------------------------------------------------------
__global__ __launch_bounds__(1024, 4)
void conv_slab_k(const unsigned short* __restrict__ in, const unsigned short* __restrict__ whp_l,
                 const float* __restrict__ raw_in, unsigned short* __restrict__ outb,
                 float* __restrict__ raw_out)
{
    __shared__ unsigned short tile[4 * PLSTR];   // 115,328 B
    __shared__ float s_red[1024];

    const int tid  = threadIdx.x;
    const int lane = tid & 63;
    const int wv   = tid >> 6;        // wave 0..15
    const int zz   = wv >> 1;         // z-plane 0..7
    const int yh   = (wv & 1) << 2;   // y-half 0 or 4
    const int row  = lane & 15;       // A: x within frag
    const int g4   = lane >> 4;       // k-chunk
    const int g    = tid & 3;
    const int vox0 = tid >> 2;        // 0..255

    const int blk = blockIdx.x;
    const int b   = blk >> 8;
    const int t   = blk & 255;
    const int x0  = (t & 3) << 4;     // 4 x-tiles of 16
    const int y0  = ((t >> 2) & 7) << 3;
    const int z0  = (t >> 5) << 3;

    // ---- stage halo 18x10x10 (norm+relu fused, cvt_pk) ----
    {
        float rs[8], sh[8];
        #pragma unroll
        for (int j = 0; j < 8; ++j) {
            int c = b * 32 + g * 8 + j;
            float sm = raw_in[c * 2], sq = raw_in[c * 2 + 1];
            float mean = sm * (1.f / 262144.f);
            float var  = sq * (1.f / 262144.f) - mean * mean;
            float r = rsqrtf(var + EPS_F);
            rs[j] = r; sh[j] = -mean * r;
        }
        #pragma unroll 1
        for (int u = 0; u < 8; ++u) {
            int vox = vox0 + u * 256;
            if (vox >= 1800) break;
            int zp = vox / 180, r2 = vox - zp * 180, yy = r2 / 18, xx = r2 - yy * 18;
            int gz = z0 + zp - 1, gy = y0 + yy - 1, gx = x0 + xx - 1;
            u32x4 w = (u32x4)0;
            if ((unsigned)gz < 64u && (unsigned)gy < 64u && (unsigned)gx < 64u) {
                u32x4 rv = *(const u32x4*)(in
                    + ((((size_t)b << 18) + (gz << 12) + (gy << 6) + gx) << 5) + (g << 3));
                #pragma unroll
                for (int k = 0; k < 4; ++k) {
                    float ve = __builtin_bit_cast(float, rv[k] << 16);
                    float vo = __builtin_bit_cast(float, rv[k] & 0xFFFF0000u);
                    float ne = fmaxf(0.f, fmaf(ve, rs[2 * k],     sh[2 * k]));
                    float no = fmaxf(0.f, fmaf(vo, rs[2 * k + 1], sh[2 * k + 1]));
                    w[k] = cvt_pk_bf16(ne, no);
                }
            }
            *(u32x4*)&tile[g * PLSTR + (vox << 3)] = w;
        }
    }
    __syncthreads();

    // ---- MFMA: 27 taps x 4 frags; incremental doff; setprio around MFMAs --
    f32x4 acc[4][2] = {};
    {
        const unsigned short* aplane = &tile[g4 * PLSTR];
        int abase[4];
        #pragma unroll
        for (int fr = 0; fr < 4; ++fr)
            abase[fr] = ((zz * 180 + (yh + fr) * 18 + row) << 3);
        const unsigned short* wrow = whp_l + row * 32 + g4 * 8;

        s16x8 wh0 = *(const s16x8*)(wrow);
        s16x8 wh1 = *(const s16x8*)(wrow + 512);

        int doff = 0, dxc = 0, dyc = 0;
        #pragma unroll 1
        for (int tap = 0; tap < 27; ++tap) {
            const unsigned short* wn = wrow + ((tap < 26) ? (tap + 1) << 10 : 26 << 10);
            s16x8 nh0 = *(const s16x8*)(wn);
            s16x8 nh1 = *(const s16x8*)(wn + 512);

            s16x8 a0 = *(const s16x8*)&aplane[abase[0] + doff];
            s16x8 a1 = *(const s16x8*)&aplane[abase[1] + doff];
            s16x8 a2 = *(const s16x8*)&aplane[abase[2] + doff];
            s16x8 a3 = *(const s16x8*)&aplane[abase[3] + doff];

            __builtin_amdgcn_s_setprio(1);
            acc[0][0] = __builtin_amdgcn_mfma_f32_16x16x32_bf16(a0, wh0, acc[0][0], 0, 0, 0);
            acc[1][0] = __builtin_amdgcn_mfma_f32_16x16x32_bf16(a1, wh0, acc[1][0], 0, 0, 0);
            acc[2][0] = __builtin_amdgcn_mfma_f32_16x16x32_bf16(a2, wh0, acc[2][0], 0, 0, 0);
            acc[3][0] = __builtin_amdgcn_mfma_f32_16x16x32_bf16(a3, wh0, acc[3][0], 0, 0, 0);
            acc[0][1] = __builtin_amdgcn_mfma_f32_16x16x32_bf16(a0, wh1, acc[0][1], 0, 0, 0);
            acc[1][1] = __builtin_amdgcn_mfma_f32_16x16x32_bf16(a1, wh1, acc[1][1], 0, 0, 0);
            acc[2][1] = __builtin_amdgcn_mfma_f32_16x16x32_bf16(a2, wh1, acc[2][1], 0, 0, 0);
            acc[3][1] = __builtin_amdgcn_mfma_f32_16x16x32_bf16(a3, wh1, acc[3][1], 0, 0, 0);
            __builtin_amdgcn_s_setprio(0);

            wh0 = nh0; wh1 = nh1;
            // advance (dz,dy,dx) incrementally: doff in shorts, voxel = 8 shorts
            ++dxc; doff += 8;
            if (dxc == 3) {
                dxc = 0; ++dyc; doff += 120;            // +row (18 vox) - 3 vox
                if (dyc == 3) { dyc = 0; doff += 1008; } // +plane (180 vox) - 3 rows
            }
        }
    }

    // ---- instance-norm partial stats ----
    {
        float s0 = 0.f, ss0 = 0.f, s1 = 0.f, ss1 = 0.f;
        #pragma unroll
        for (int fr = 0; fr < 4; ++fr)
            #pragma unroll
            for (int q = 0; q < 4; ++q) {
                float v0 = acc[fr][0][q], v1 = acc[fr][1][q];
                s0 += v0; ss0 += v0 * v0; s1 += v1; ss1 += v1 * v1;
            }
        s0 += __shfl_xor(s0, 16); s0 += __shfl_xor(s0, 32);
        ss0 += __shfl_xor(ss0, 16); ss0 += __shfl_xor(ss0, 32);
        s1 += __shfl_xor(s1, 16); s1 += __shfl_xor(s1, 32);
        ss1 += __shfl_xor(ss1, 16); ss1 += __shfl_xor(ss1, 32);
        if (lane < 16) {
            s_red[(wv * 32 + 2 * row) * 2]         = s0;
            s_red[(wv * 32 + 2 * row) * 2 + 1]     = ss0;
            s_red[(wv * 32 + 2 * row + 1) * 2]     = s1;
            s_red[(wv * 32 + 2 * row + 1) * 2 + 1] = ss1;
        }
    }

    // ---- packed channel-pair stores: voxel x = g4*4+qq, y = yh+fr, z = zz --
    #pragma unroll
    for (int fr = 0; fr < 4; ++fr) {
        unsigned short* ob = outb
            + ((((size_t)b << 18) + ((size_t)(z0 + zz) << 12) + ((y0 + yh + fr) << 6) + x0) << 5)
            + (row << 1);
        #pragma unroll
        for (int qq = 0; qq < 4; ++qq) {
            unsigned pk = cvt_pk_bf16(acc[fr][0][qq], acc[fr][1][qq]);
            *(unsigned*)(ob + ((g4 * 4 + qq) << 5)) = pk;
        }
    }

    __syncthreads();
    if (tid < 64) {
        int n = tid & 31, sel = tid >> 5;
        float tot = 0.f;
        #pragma unroll
        for (int w = 0; w < 16; ++w) tot += s_red[(w * 32 + n) * 2 + sel];
        atomicAdd(&raw_out[(b * 32 + n) * 2 + sel], tot);
    }
}

// ---------------------------------------------------------------------------
// ROI pooling GEMM with fused mask read + fused stats finalization.
// ---------------------------------------------------------------------------
__global__ __launch_bounds__(256)
void pool_mfma_k(const unsigned short* __restrict__ emb, const float* __restrict__ raw3,
                 const float* __restrict__ mask, float* __restrict__ part,
                 float* __restrict__ cntp)
{
    __shared__ unsigned short Ald[64 * 136];
    __shared__ unsigned short Bld[96 * 136];
    __shared__ float s_ns[128];

    const int tid  = threadIdx.x;
    const int lane = tid & 63, wv = tid >> 6;
    const int row  = lane & 15, g4 = lane >> 4;

    if (tid < 64) {
        float sm = raw3[tid * 2], sq = raw3[tid * 2 + 1];
        float mean = sm * (1.f / 262144.f);
        float var  = sq * (1.f / 262144.f) - mean * mean;
        float r = rsqrtf(var + EPS_F);
        s_ns[tid]      = r;
        s_ns[64 + tid] = -mean * r;
    }

    f32x4 acc[6] = {};
    float csum[6] = {};

    for (int ch = 0; ch < 4; ++ch) {
        const int s0 = (blockIdx.x * 4 + ch) << 7;
        __syncthreads();
        for (int i = tid; i < 1024; i += 256) {
            int bb = i >> 9, v = (i >> 2) & 127, g = i & 3;
            u32x4 rv = *(const u32x4*)(emb + (((size_t)bb << 18) + (size_t)(s0 + v)) * 32 + (g << 3));
            #pragma unroll
            for (int k = 0; k < 4; ++k) {
                int bc = bb * 32 + (g << 3) + 2 * k;
                float ve = __builtin_bit_cast(float, rv[k] << 16);
                float vo = __builtin_bit_cast(float, rv[k] & 0xFFFF0000u);
                float ne = fmaxf(0.f, fmaf(ve, s_ns[bc],     s_ns[64 + bc]));
                float no = fmaxf(0.f, fmaf(vo, s_ns[bc + 1], s_ns[64 + bc + 1]));
                unsigned pk = cvt_pk_bf16(ne, no);
                Ald[bc * 136 + v]       = (unsigned short)pk;
                Ald[(bc + 1) * 136 + v] = (unsigned short)(pk >> 16);
            }
        }
        #pragma unroll
        for (int k = 0; k < 6; ++k) {
            int i = tid + k * 256;
            int r = i >> 4, bs = i & 15;
            s16x8 vec = (s16x8)0;
            if (r < 90) {
                const float* mp = mask + (size_t)r * S_TOT + s0 + bs * 8;
                float4 m0 = *(const float4*)mp;
                float4 m1 = *(const float4*)(mp + 4);
                vec[0] = (m0.x != 0.f) ? (short)0x3F80 : (short)0;
                vec[1] = (m0.y != 0.f) ? (short)0x3F80 : (short)0;
                vec[2] = (m0.z != 0.f) ? (short)0x3F80 : (short)0;
                vec[3] = (m0.w != 0.f) ? (short)0x3F80 : (short)0;
                vec[4] = (m1.x != 0.f) ? (short)0x3F80 : (short)0;
                vec[5] = (m1.y != 0.f) ? (short)0x3F80 : (short)0;
                vec[6] = (m1.z != 0.f) ? (short)0x3F80 : (short)0;
                vec[7] = (m1.w != 0.f) ? (short)0x3F80 : (short)0;
                csum[k] += m0.x + m0.y + m0.z + m0.w + m1.x + m1.y + m1.z + m1.w;
            }
            *(s16x8*)&Bld[r * 136 + bs * 8] = vec;
        }
        __syncthreads();
        #pragma unroll
        for (int kk = 0; kk < 4; ++kk) {
            s16x8 a = *(const s16x8*)&Ald[(wv * 16 + row) * 136 + kk * 32 + g4 * 8];
            #pragma unroll
            for (int j = 0; j < 6; ++j) {
                s16x8 bb = *(const s16x8*)&Bld[(j * 16 + row) * 136 + kk * 32 + g4 * 8];
                acc[j] = __builtin_amdgcn_mfma_f32_16x16x32_bf16(a, bb, acc[j], 0, 0, 0);
            }
        }
    }
    #pragma unroll
    for (int k = 0; k < 6; ++k) {
        float c = csum[k];
        c += __shfl_xor(c, 1); c += __shfl_xor(c, 2);
        c += __shfl_xor(c, 4); c += __shfl_xor(c, 8);
        if ((tid & 15) == 0)
            cntp[(size_t)blockIdx.x * 96 + (tid >> 4) + k * 16] = c;
    }
    #pragma unroll
    for (int j = 0; j < 6; ++j) {
        *(f32x4*)&part[((size_t)blockIdx.x * 96 + j * 16 + row) * 64 + wv * 16 + g4 * 4]
            = acc[j];
    }
}

// ---------------------------------------------------------------------------
// Per-ROI partial+count reduction (256-thread wide) + gated MLP + projection.
// ---------------------------------------------------------------------------
__global__ __launch_bounds__(256)
void mlp_k(const float* __restrict__ part, const float* __restrict__ cntp,
           const float* __restrict__ w1, const float* __restrict__ b1,
           const float* __restrict__ w2, const float* __restrict__ b2,
           const float* __restrict__ pw1, const float* __restrict__ pb1,
           const float* __restrict__ pw2, const float* __restrict__ pb2,
           float* __restrict__ out)
{
    const int r   = blockIdx.x % 90;
    const int b   = blockIdx.x / 90;
    const int tid = threadIdx.x;
    __shared__ float sred[8 * 32];
    __shared__ float scnt[4];
    __shared__ float roi_s[32], h_s[64], f_s[32], p_s[64];

    {
        float csp = 0.f;
        for (int p = tid; p < NPART; p += 256) csp += cntp[(size_t)p * 96 + r];
        #pragma unroll
        for (int off = 32; off > 0; off >>= 1) csp += __shfl_xor(csp, off);
        if ((tid & 63) == 0) scnt[tid >> 6] = csp;
    }
    {
        const int c = tid & 31, seg = tid >> 5;
        const float* pp = part + ((size_t)(seg * (NPART / 8)) * 96 + r) * 64 + b * 32 + c;
        float s = 0.f;
        #pragma unroll 4
        for (int p = 0; p < NPART / 8; ++p) s += pp[(size_t)p * 6144];
        sred[seg * 32 + c] = s;
    }
    __syncthreads();
    if (tid < 32) {
        float cs = scnt[0] + scnt[1] + scnt[2] + scnt[3];
        float t = 0.f;
        #pragma unroll
        for (int k = 0; k < 8; ++k) t += sred[k * 32 + tid];
        roi_s[tid] = t / cs;
    }
    __syncthreads();
    if (tid < 64) {
        float s = b1[r * 64 + tid];
        for (int c = 0; c < 32; ++c)
            s = fmaf(roi_s[c], w1[(r * 32 + c) * 64 + tid], s);
        h_s[tid] = fmaxf(s, 0.f);
    }
    __syncthreads();
    if (tid < 32) {
        float s = b2[r * 32 + tid];
        for (int j = 0; j < 64; ++j)
            s = fmaf(h_s[j], w2[(r * 64 + j) * 32 + tid], s);
        float gate = 1.f / (1.f + expf(-s));
        f_s[tid] = gate * roi_s[tid];
    }
    __syncthreads();
    if (tid < 64) {
        float s = pb1[r * 64 + tid];
        for (int c = 0; c < 32; ++c)
            s = fmaf(f_s[c], pw1[(r * 32 + c) * 64 + tid], s);
        p_s[tid] = fmaxf(s, 0.f);
    }
    __syncthreads();
    if (tid < 32) {
        float s = pb2[r * 32 + tid];
        for (int j = 0; j < 64; ++j)
            s = fmaf(p_s[j], pw2[(r * 64 + j) * 32 + tid], s);
        out[((size_t)b * 90 + r) * 32 + tid] = s;
    }
}

// ---------------------------------------------------------------------------
extern "C" void kernel_launch(void* const* d_in, const int* in_sizes, int n_in,
                              void* d_out, int out_size, void* d_ws, size_t ws_size,
                              hipStream_t stream)
{
    const float* data    = (const float*)d_in[0];
    const float* mask    = (const float*)d_in[1];
    const float* conv0_w = (const float*)d_in[2];
    const float* convs_w = (const float*)d_in[4];
    const float* sw1 = (const float*)d_in[6];
    const float* sb1 = (const float*)d_in[7];
    const float* sw2 = (const float*)d_in[8];
    const float* sb2 = (const float*)d_in[9];
    const float* pw1 = (const float*)d_in[10];
    const float* pb1 = (const float*)d_in[11];
    const float* pw2 = (const float*)d_in[12];
    const float* pb2 = (const float*)d_in[13];
    float* out = (float*)d_out;

    float* ws = (float*)d_ws;
    unsigned short* bufA = (unsigned short*)ws;                  // 16,777,216 bf16
    unsigned short* bufB = (unsigned short*)(ws + 8388608);      // 16,777,216 bf16
    unsigned short* wpad = (unsigned short*)(ws + 16777216);     // conv0 weights
    unsigned short* whp  = (unsigned short*)(ws + 16887808);     // packed hi (82,944)
    float* raw   = ws + 16929280;        // 512 (4 layers x 128)
    float* part  = ws + 17825792;        // NPART*96*64 floats
    float* cntp  = part + 3145728;       // NPART*96 floats

    hipMemsetAsync(raw, 0, 512 * sizeof(float), stream);
    prep_w_k<<<332, 256, 0, stream>>>(conv0_w, convs_w, wpad, whp);

    // layer 0: data(fp32) -> bufA, raw sums -> raw[0..127]
    conv0_k<<<512, 512, 0, stream>>>(data, wpad, bufA, raw);
    // layer 1: bufA -> bufB (stats fused from raw)
    conv_slab_k<<<512, 1024, 0, stream>>>(bufA, whp, raw, bufB, raw + 128);
    // layer 2: bufB -> bufA
    conv_slab_k<<<512, 1024, 0, stream>>>(bufB, whp + 27648, raw + 128, bufA, raw + 256);
    // layer 3: bufA -> bufB
    conv_slab_k<<<512, 1024, 0, stream>>>(bufA, whp + 2 * 27648, raw + 256, bufB, raw + 384);

    // ROI pooling GEMM (stats fused from raw+384) -> partials + counts
    pool_mfma_k<<<NPART, 256, 0, stream>>>(bufB, raw + 384, mask, part, cntp);

    // per-ROI partial reduction + MLPs
    mlp_k<<<180, 256, 0, stream>>>(part, cntp, sw1, sb1, sw2, sb2,
                                   pw1, pb1, pw2, pb2, out);
}

// Round 20
// 212.964 us; speedup vs baseline: 1.1290x; 1.0067x over previous
//
#include <hip/hip_runtime.h>
#include <hip/hip_bf16.h>
#include <math.h>

#define S_TOT 262144   // 64^3
#define EPS_F 1e-5f
#define NPART 512      // pool partial-K blocks
#define PLSTR 14416    // LDS plane stride in shorts (28832B ≡ 32B mod 128)

typedef __attribute__((ext_vector_type(8))) short s16x8;
typedef __attribute__((ext_vector_type(4))) float f32x4;
typedef __attribute__((ext_vector_type(4))) unsigned u32x4;

__device__ __forceinline__ unsigned short f2bf(float f) {   // RNE, manual (prep only)
    unsigned u = __builtin_bit_cast(unsigned, f);
    unsigned r = (u + 0x7FFFu + ((u >> 16) & 1u)) >> 16;
    return (unsigned short)r;
}
__device__ __forceinline__ float bf2f(unsigned short u) {
    return __builtin_bit_cast(float, ((unsigned)u) << 16);
}
// HW packed convert: low16 = bf16(a), high16 = bf16(b), RNE.
__device__ __forceinline__ unsigned cvt_pk_bf16(float a, float b) {
    unsigned r;
    asm("v_cvt_pk_bf16_f32 %0, %1, %2" : "=v"(r) : "v"(a), "v"(b));
    return r;
}

// ---------------------------------------------------------------------------
// Weight prep.
// Layer 0: w0[hi|lo][brow][k=tap(32,pad0)] at wpad[0..2047]  (hi+lo used).
// Layers 1-3: PACKED hi-only at whp[(layer-1)*27648 + tap*1024 + brow*32 + cin].
// brow(cout) = ((cout&1)<<4) | (cout>>1).
// ---------------------------------------------------------------------------
__global__ __launch_bounds__(256)
void prep_w_k(const float* __restrict__ conv0_w, const float* __restrict__ convs_w,
              unsigned short* __restrict__ wpad, unsigned short* __restrict__ whp)
{
    int idx = blockIdx.x * 256 + threadIdx.x;
    if (idx < 2048) {
        int brow = idx >> 5, k = idx & 31;
        int cout = 2 * (brow & 15) + (brow >> 4);
        float wv = (k < 27) ? conv0_w[cout * 27 + k] : 0.f;
        unsigned short hi = f2bf(wv);
        unsigned short lo = f2bf(wv - bf2f(hi));
        wpad[brow * 32 + k]        = hi;
        wpad[1024 + brow * 32 + k] = lo;
        return;
    }
    int j = idx - 2048;
    if (j >= 3 * 27648) return;
    int layer = j / 27648 + 1;
    int rem   = j % 27648;
    int tap   = rem >> 10;
    int cout  = (rem >> 5) & 31;
    int cin   = rem & 31;
    float wv = convs_w[(((layer - 1) * 32 + cout) * 32 + cin) * 27 + tap];
    unsigned short hi = f2bf(wv);
    int brow = ((cout & 1) << 4) | (cout >> 1);
    whp[(size_t)(layer - 1) * 27648 + tap * 1024 + brow * 32 + cin] = hi;
}

// ---------------------------------------------------------------------------
// Layer 0: cin=1 im2col over taps (K = 27 taps padded to 32), hi+lo.
// 512 blocks (8x8x16 slab), 512 threads, wave wv owns z-planes {2wv,2wv+1}.
// ---------------------------------------------------------------------------
__global__ __launch_bounds__(512, 2)
void conv0_k(const float* __restrict__ in, const unsigned short* __restrict__ w0,
             unsigned short* __restrict__ outb, float* __restrict__ raw_out)
{
    __shared__ unsigned short sc[1824];
    __shared__ float s_red[512];

    const int tid  = threadIdx.x;
    const int lane = tid & 63;
    const int wv   = tid >> 6;
    const int row  = lane & 15;
    const int g4   = lane >> 4;

    const int blk = blockIdx.x;
    const int b   = blk >> 8;
    const int t   = blk & 255;
    const int x0  = (t & 7) << 3;
    const int y0  = ((t >> 3) & 7) << 3;
    const int z0  = (t >> 6) << 4;

    for (int i = tid; i < 1800; i += 512) {
        int zz = i / 100, r2 = i - zz * 100, yy = r2 / 10, xx = r2 - yy * 10;
        int gz = z0 + zz - 1, gy = y0 + yy - 1, gx = x0 + xx - 1;
        float v = 0.f;
        if ((unsigned)gz < 64u && (unsigned)gy < 64u && (unsigned)gx < 64u)
            v = in[((size_t)b << 18) + (gz << 12) + (gy << 6) + gx];
        sc[i] = (unsigned short)cvt_pk_bf16(v, v);
    }
    __syncthreads();

    int dvox[8];
    #pragma unroll
    for (int j = 0; j < 8; ++j) {
        int tap = g4 * 8 + j;
        if (tap < 27) {
            int dz = tap / 9, r9 = tap - dz * 9, dy = r9 / 3, dx = r9 - dy * 3;
            dvox[j] = dz * 100 + dy * 10 + dx;
        } else dvox[j] = 0;
    }

    s16x8 wh0 = *(const s16x8*)(w0 + row * 32 + g4 * 8);
    s16x8 wh1 = *(const s16x8*)(w0 + (16 + row) * 32 + g4 * 8);
    s16x8 wl0 = *(const s16x8*)(w0 + 1024 + row * 32 + g4 * 8);
    s16x8 wl1 = *(const s16x8*)(w0 + 1024 + (16 + row) * 32 + g4 * 8);

    f32x4 acc[2][4][2] = {};
    #pragma unroll
    for (int pl = 0; pl < 2; ++pl) {
        #pragma unroll
        for (int f = 0; f < 4; ++f) {
            int vvx = f * 16 + row;
            int base = (2 * wv + pl) * 100 + (vvx >> 3) * 10 + (vvx & 7);
            s16x8 a;
            #pragma unroll
            for (int j = 0; j < 8; ++j) a[j] = (short)sc[base + dvox[j]];
            acc[pl][f][0] = __builtin_amdgcn_mfma_f32_16x16x32_bf16(a, wh0, acc[pl][f][0], 0, 0, 0);
            acc[pl][f][0] = __builtin_amdgcn_mfma_f32_16x16x32_bf16(a, wl0, acc[pl][f][0], 0, 0, 0);
            acc[pl][f][1] = __builtin_amdgcn_mfma_f32_16x16x32_bf16(a, wh1, acc[pl][f][1], 0, 0, 0);
            acc[pl][f][1] = __builtin_amdgcn_mfma_f32_16x16x32_bf16(a, wl1, acc[pl][f][1], 0, 0, 0);
        }
    }

    {
        float s0 = 0.f, ss0 = 0.f, s1 = 0.f, ss1 = 0.f;
        #pragma unroll
        for (int pl = 0; pl < 2; ++pl)
            #pragma unroll
            for (int f = 0; f < 4; ++f)
                #pragma unroll
                for (int q = 0; q < 4; ++q) {
                    float v0 = acc[pl][f][0][q], v1 = acc[pl][f][1][q];
                    s0 += v0; ss0 += v0 * v0; s1 += v1; ss1 += v1 * v1;
                }
        s0 += __shfl_xor(s0, 16); s0 += __shfl_xor(s0, 32);
        ss0 += __shfl_xor(ss0, 16); ss0 += __shfl_xor(ss0, 32);
        s1 += __shfl_xor(s1, 16); s1 += __shfl_xor(s1, 32);
        ss1 += __shfl_xor(ss1, 16); ss1 += __shfl_xor(ss1, 32);
        if (lane < 16) {
            s_red[(wv * 32 + 2 * row) * 2]         = s0;
            s_red[(wv * 32 + 2 * row) * 2 + 1]     = ss0;
            s_red[(wv * 32 + 2 * row + 1) * 2]     = s1;
            s_red[(wv * 32 + 2 * row + 1) * 2 + 1] = ss1;
        }
    }

    #pragma unroll
    for (int pl = 0; pl < 2; ++pl) {
        int zp = 2 * wv + pl;
        unsigned short* ob = outb
            + ((((size_t)b << 18) + ((size_t)(z0 + zp) << 12) + (y0 << 6) + x0) << 5)
            + (row << 1);
        #pragma unroll
        for (int f = 0; f < 4; ++f) {
            #pragma unroll
            for (int qq = 0; qq < 4; ++qq) {
                int u = g4 * 4 + qq;
                int yy = f * 2 + (u >> 3), xx = u & 7;
                unsigned pk = cvt_pk_bf16(acc[pl][f][0][qq], acc[pl][f][1][qq]);
                *(unsigned*)(ob + ((yy << 6) + xx) * 32) = pk;
            }
        }
    }

    __syncthreads();
    if (tid < 64) {
        int n = tid & 31, sel = tid >> 5;
        float tot = 0.f;
        #pragma unroll
        for (int w = 0; w < 8; ++w) tot += s_red[(w * 32 + n) * 2 + sel];
        atomicAdd(&raw_out[(b * 32 + n) * 2 + sel], tot);
    }
}

// ---------------------------------------------------------------------------
// Mid conv layers: 16x8x8 X-WIDE tile, 1024 threads = 16 waves.  Y-REUSE
// tap loop: order (dz,dx,dy); per (dz,dx) read the 6 distinct tile rows
// (yh + fr + dy spans 6 rows) ONCE into registers, then 3x4 MFMAs reuse
// them -> ds_read count HALVED (54 vs 108 per thread).  Frag row = 16
// consecutive x-voxels -> conflict-free contiguous 256B reads.
// HI-ONLY packed weights; stats fused; cvt_pk converts; setprio on MFMAs.
// ---------------------------------------------------------------------------
__global__ __launch_bounds__(1024, 4)
void conv_slab_k(const unsigned short* __restrict__ in, const unsigned short* __restrict__ whp_l,
                 const float* __restrict__ raw_in, unsigned short* __restrict__ outb,
                 float* __restrict__ raw_out)
{
    __shared__ unsigned short tile[4 * PLSTR];   // 115,328 B
    __shared__ float s_red[1024];

    const int tid  = threadIdx.x;
    const int lane = tid & 63;
    const int wv   = tid >> 6;        // wave 0..15
    const int zz   = wv >> 1;         // z-plane 0..7
    const int yh   = (wv & 1) << 2;   // y-half 0 or 4
    const int row  = lane & 15;       // A: x within frag
    const int g4   = lane >> 4;       // k-chunk
    const int g    = tid & 3;
    const int vox0 = tid >> 2;        // 0..255

    const int blk = blockIdx.x;
    const int b   = blk >> 8;
    const int t   = blk & 255;
    const int x0  = (t & 3) << 4;     // 4 x-tiles of 16
    const int y0  = ((t >> 2) & 7) << 3;
    const int z0  = (t >> 5) << 3;

    // ---- stage halo 18x10x10 (norm+relu fused, cvt_pk) ----
    {
        float rs[8], sh[8];
        #pragma unroll
        for (int j = 0; j < 8; ++j) {
            int c = b * 32 + g * 8 + j;
            float sm = raw_in[c * 2], sq = raw_in[c * 2 + 1];
            float mean = sm * (1.f / 262144.f);
            float var  = sq * (1.f / 262144.f) - mean * mean;
            float r = rsqrtf(var + EPS_F);
            rs[j] = r; sh[j] = -mean * r;
        }
        #pragma unroll 1
        for (int u = 0; u < 8; ++u) {
            int vox = vox0 + u * 256;
            if (vox >= 1800) break;
            int zp = vox / 180, r2 = vox - zp * 180, yy = r2 / 18, xx = r2 - yy * 18;
            int gz = z0 + zp - 1, gy = y0 + yy - 1, gx = x0 + xx - 1;
            u32x4 w = (u32x4)0;
            if ((unsigned)gz < 64u && (unsigned)gy < 64u && (unsigned)gx < 64u) {
                u32x4 rv = *(const u32x4*)(in
                    + ((((size_t)b << 18) + (gz << 12) + (gy << 6) + gx) << 5) + (g << 3));
                #pragma unroll
                for (int k = 0; k < 4; ++k) {
                    float ve = __builtin_bit_cast(float, rv[k] << 16);
                    float vo = __builtin_bit_cast(float, rv[k] & 0xFFFF0000u);
                    float ne = fmaxf(0.f, fmaf(ve, rs[2 * k],     sh[2 * k]));
                    float no = fmaxf(0.f, fmaf(vo, rs[2 * k + 1], sh[2 * k + 1]));
                    w[k] = cvt_pk_bf16(ne, no);
                }
            }
            *(u32x4*)&tile[g * PLSTR + (vox << 3)] = w;
        }
    }
    __syncthreads();

    // ---- MFMA with y-reuse: for (dz,dx), read 6 rows once, 3x4 MFMAs ----
    f32x4 acc[4][2] = {};
    {
        const unsigned short* aplane = &tile[g4 * PLSTR];
        const unsigned short* wrow = whp_l + row * 32 + g4 * 8;

        #pragma unroll 1
        for (int dz = 0; dz < 3; ++dz) {
            #pragma unroll 1
            for (int dx = 0; dx < 3; ++dx) {
                // 6 distinct tile rows for (fr + dy) in 0..5
                const int base = (((zz + dz) * 180 + yh * 18 + row + dx) << 3);
                s16x8 a6[6];
                #pragma unroll
                for (int r6 = 0; r6 < 6; ++r6)
                    a6[r6] = *(const s16x8*)&aplane[base + r6 * 144];

                #pragma unroll
                for (int dy = 0; dy < 3; ++dy) {
                    const int tap = (dz * 3 + dy) * 3 + dx;
                    s16x8 w0v = *(const s16x8*)(wrow + tap * 1024);
                    s16x8 w1v = *(const s16x8*)(wrow + tap * 1024 + 512);
                    __builtin_amdgcn_s_setprio(1);
                    acc[0][0] = __builtin_amdgcn_mfma_f32_16x16x32_bf16(a6[dy],     w0v, acc[0][0], 0, 0, 0);
                    acc[1][0] = __builtin_amdgcn_mfma_f32_16x16x32_bf16(a6[dy + 1], w0v, acc[1][0], 0, 0, 0);
                    acc[2][0] = __builtin_amdgcn_mfma_f32_16x16x32_bf16(a6[dy + 2], w0v, acc[2][0], 0, 0, 0);
                    acc[3][0] = __builtin_amdgcn_mfma_f32_16x16x32_bf16(a6[dy + 3], w0v, acc[3][0], 0, 0, 0);
                    acc[0][1] = __builtin_amdgcn_mfma_f32_16x16x32_bf16(a6[dy],     w1v, acc[0][1], 0, 0, 0);
                    acc[1][1] = __builtin_amdgcn_mfma_f32_16x16x32_bf16(a6[dy + 1], w1v, acc[1][1], 0, 0, 0);
                    acc[2][1] = __builtin_amdgcn_mfma_f32_16x16x32_bf16(a6[dy + 2], w1v, acc[2][1], 0, 0, 0);
                    acc[3][1] = __builtin_amdgcn_mfma_f32_16x16x32_bf16(a6[dy + 3], w1v, acc[3][1], 0, 0, 0);
                    __builtin_amdgcn_s_setprio(0);
                }
            }
        }
    }

    // ---- instance-norm partial stats ----
    {
        float s0 = 0.f, ss0 = 0.f, s1 = 0.f, ss1 = 0.f;
        #pragma unroll
        for (int fr = 0; fr < 4; ++fr)
            #pragma unroll
            for (int q = 0; q < 4; ++q) {
                float v0 = acc[fr][0][q], v1 = acc[fr][1][q];
                s0 += v0; ss0 += v0 * v0; s1 += v1; ss1 += v1 * v1;
            }
        s0 += __shfl_xor(s0, 16); s0 += __shfl_xor(s0, 32);
        ss0 += __shfl_xor(ss0, 16); ss0 += __shfl_xor(ss0, 32);
        s1 += __shfl_xor(s1, 16); s1 += __shfl_xor(s1, 32);
        ss1 += __shfl_xor(ss1, 16); ss1 += __shfl_xor(ss1, 32);
        if (lane < 16) {
            s_red[(wv * 32 + 2 * row) * 2]         = s0;
            s_red[(wv * 32 + 2 * row) * 2 + 1]     = ss0;
            s_red[(wv * 32 + 2 * row + 1) * 2]     = s1;
            s_red[(wv * 32 + 2 * row + 1) * 2 + 1] = ss1;
        }
    }

    // ---- packed channel-pair stores: voxel x = g4*4+qq, y = yh+fr, z = zz --
    #pragma unroll
    for (int fr = 0; fr < 4; ++fr) {
        unsigned short* ob = outb
            + ((((size_t)b << 18) + ((size_t)(z0 + zz) << 12) + ((y0 + yh + fr) << 6) + x0) << 5)
            + (row << 1);
        #pragma unroll
        for (int qq = 0; qq < 4; ++qq) {
            unsigned pk = cvt_pk_bf16(acc[fr][0][qq], acc[fr][1][qq]);
            *(unsigned*)(ob + ((g4 * 4 + qq) << 5)) = pk;
        }
    }

    __syncthreads();
    if (tid < 64) {
        int n = tid & 31, sel = tid >> 5;
        float tot = 0.f;
        #pragma unroll
        for (int w = 0; w < 16; ++w) tot += s_red[(w * 32 + n) * 2 + sel];
        atomicAdd(&raw_out[(b * 32 + n) * 2 + sel], tot);
    }
}

// ---------------------------------------------------------------------------
// ROI pooling GEMM with fused mask read + fused stats finalization.
// ---------------------------------------------------------------------------
__global__ __launch_bounds__(256)
void pool_mfma_k(const unsigned short* __restrict__ emb, const float* __restrict__ raw3,
                 const float* __restrict__ mask, float* __restrict__ part,
                 float* __restrict__ cntp)
{
    __shared__ unsigned short Ald[64 * 136];
    __shared__ unsigned short Bld[96 * 136];
    __shared__ float s_ns[128];

    const int tid  = threadIdx.x;
    const int lane = tid & 63, wv = tid >> 6;
    const int row  = lane & 15, g4 = lane >> 4;

    if (tid < 64) {
        float sm = raw3[tid * 2], sq = raw3[tid * 2 + 1];
        float mean = sm * (1.f / 262144.f);
        float var  = sq * (1.f / 262144.f) - mean * mean;
        float r = rsqrtf(var + EPS_F);
        s_ns[tid]      = r;
        s_ns[64 + tid] = -mean * r;
    }

    f32x4 acc[6] = {};
    float csum[6] = {};

    for (int ch = 0; ch < 4; ++ch) {
        const int s0 = (blockIdx.x * 4 + ch) << 7;
        __syncthreads();
        for (int i = tid; i < 1024; i += 256) {
            int bb = i >> 9, v = (i >> 2) & 127, g = i & 3;
            u32x4 rv = *(const u32x4*)(emb + (((size_t)bb << 18) + (size_t)(s0 + v)) * 32 + (g << 3));
            #pragma unroll
            for (int k = 0; k < 4; ++k) {
                int bc = bb * 32 + (g << 3) + 2 * k;
                float ve = __builtin_bit_cast(float, rv[k] << 16);
                float vo = __builtin_bit_cast(float, rv[k] & 0xFFFF0000u);
                float ne = fmaxf(0.f, fmaf(ve, s_ns[bc],     s_ns[64 + bc]));
                float no = fmaxf(0.f, fmaf(vo, s_ns[bc + 1], s_ns[64 + bc + 1]));
                unsigned pk = cvt_pk_bf16(ne, no);
                Ald[bc * 136 + v]       = (unsigned short)pk;
                Ald[(bc + 1) * 136 + v] = (unsigned short)(pk >> 16);
            }
        }
        #pragma unroll
        for (int k = 0; k < 6; ++k) {
            int i = tid + k * 256;
            int r = i >> 4, bs = i & 15;
            s16x8 vec = (s16x8)0;
            if (r < 90) {
                const float* mp = mask + (size_t)r * S_TOT + s0 + bs * 8;
                float4 m0 = *(const float4*)mp;
                float4 m1 = *(const float4*)(mp + 4);
                vec[0] = (m0.x != 0.f) ? (short)0x3F80 : (short)0;
                vec[1] = (m0.y != 0.f) ? (short)0x3F80 : (short)0;
                vec[2] = (m0.z != 0.f) ? (short)0x3F80 : (short)0;
                vec[3] = (m0.w != 0.f) ? (short)0x3F80 : (short)0;
                vec[4] = (m1.x != 0.f) ? (short)0x3F80 : (short)0;
                vec[5] = (m1.y != 0.f) ? (short)0x3F80 : (short)0;
                vec[6] = (m1.z != 0.f) ? (short)0x3F80 : (short)0;
                vec[7] = (m1.w != 0.f) ? (short)0x3F80 : (short)0;
                csum[k] += m0.x + m0.y + m0.z + m0.w + m1.x + m1.y + m1.z + m1.w;
            }
            *(s16x8*)&Bld[r * 136 + bs * 8] = vec;
        }
        __syncthreads();
        #pragma unroll
        for (int kk = 0; kk < 4; ++kk) {
            s16x8 a = *(const s16x8*)&Ald[(wv * 16 + row) * 136 + kk * 32 + g4 * 8];
            #pragma unroll
            for (int j = 0; j < 6; ++j) {
                s16x8 bb = *(const s16x8*)&Bld[(j * 16 + row) * 136 + kk * 32 + g4 * 8];
                acc[j] = __builtin_amdgcn_mfma_f32_16x16x32_bf16(a, bb, acc[j], 0, 0, 0);
            }
        }
    }
    #pragma unroll
    for (int k = 0; k < 6; ++k) {
        float c = csum[k];
        c += __shfl_xor(c, 1); c += __shfl_xor(c, 2);
        c += __shfl_xor(c, 4); c += __shfl_xor(c, 8);
        if ((tid & 15) == 0)
            cntp[(size_t)blockIdx.x * 96 + (tid >> 4) + k * 16] = c;
    }
    #pragma unroll
    for (int j = 0; j < 6; ++j) {
        *(f32x4*)&part[((size_t)blockIdx.x * 96 + j * 16 + row) * 64 + wv * 16 + g4 * 4]
            = acc[j];
    }
}

// ---------------------------------------------------------------------------
// Per-ROI partial+count reduction (256-thread wide) + gated MLP + projection.
// ---------------------------------------------------------------------------
__global__ __launch_bounds__(256)
void mlp_k(const float* __restrict__ part, const float* __restrict__ cntp,
           const float* __restrict__ w1, const float* __restrict__ b1,
           const float* __restrict__ w2, const float* __restrict__ b2,
           const float* __restrict__ pw1, const float* __restrict__ pb1,
           const float* __restrict__ pw2, const float* __restrict__ pb2,
           float* __restrict__ out)
{
    const int r   = blockIdx.x % 90;
    const int b   = blockIdx.x / 90;
    const int tid = threadIdx.x;
    __shared__ float sred[8 * 32];
    __shared__ float scnt[4];
    __shared__ float roi_s[32], h_s[64], f_s[32], p_s[64];

    {
        float csp = 0.f;
        for (int p = tid; p < NPART; p += 256) csp += cntp[(size_t)p * 96 + r];
        #pragma unroll
        for (int off = 32; off > 0; off >>= 1) csp += __shfl_xor(csp, off);
        if ((tid & 63) == 0) scnt[tid >> 6] = csp;
    }
    {
        const int c = tid & 31, seg = tid >> 5;
        const float* pp = part + ((size_t)(seg * (NPART / 8)) * 96 + r) * 64 + b * 32 + c;
        float s = 0.f;
        #pragma unroll 4
        for (int p = 0; p < NPART / 8; ++p) s += pp[(size_t)p * 6144];
        sred[seg * 32 + c] = s;
    }
    __syncthreads();
    if (tid < 32) {
        float cs = scnt[0] + scnt[1] + scnt[2] + scnt[3];
        float t = 0.f;
        #pragma unroll
        for (int k = 0; k < 8; ++k) t += sred[k * 32 + tid];
        roi_s[tid] = t / cs;
    }
    __syncthreads();
    if (tid < 64) {
        float s = b1[r * 64 + tid];
        for (int c = 0; c < 32; ++c)
            s = fmaf(roi_s[c], w1[(r * 32 + c) * 64 + tid], s);
        h_s[tid] = fmaxf(s, 0.f);
    }
    __syncthreads();
    if (tid < 32) {
        float s = b2[r * 32 + tid];
        for (int j = 0; j < 64; ++j)
            s = fmaf(h_s[j], w2[(r * 64 + j) * 32 + tid], s);
        float gate = 1.f / (1.f + expf(-s));
        f_s[tid] = gate * roi_s[tid];
    }
    __syncthreads();
    if (tid < 64) {
        float s = pb1[r * 64 + tid];
        for (int c = 0; c < 32; ++c)
            s = fmaf(f_s[c], pw1[(r * 32 + c) * 64 + tid], s);
        p_s[tid] = fmaxf(s, 0.f);
    }
    __syncthreads();
    if (tid < 32) {
        float s = pb2[r * 32 + tid];
        for (int j = 0; j < 64; ++j)
            s = fmaf(p_s[j], pw2[(r * 64 + j) * 32 + tid], s);
        out[((size_t)b * 90 + r) * 32 + tid] = s;
    }
}

// ---------------------------------------------------------------------------
extern "C" void kernel_launch(void* const* d_in, const int* in_sizes, int n_in,
                              void* d_out, int out_size, void* d_ws, size_t ws_size,
                              hipStream_t stream)
{
    const float* data    = (const float*)d_in[0];
    const float* mask    = (const float*)d_in[1];
    const float* conv0_w = (const float*)d_in[2];
    const float* convs_w = (const float*)d_in[4];
    const float* sw1 = (const float*)d_in[6];
    const float* sb1 = (const float*)d_in[7];
    const float* sw2 = (const float*)d_in[8];
    const float* sb2 = (const float*)d_in[9];
    const float* pw1 = (const float*)d_in[10];
    const float* pb1 = (const float*)d_in[11];
    const float* pw2 = (const float*)d_in[12];
    const float* pb2 = (const float*)d_in[13];
    float* out = (float*)d_out;

    float* ws = (float*)d_ws;
    unsigned short* bufA = (unsigned short*)ws;                  // 16,777,216 bf16
    unsigned short* bufB = (unsigned short*)(ws + 8388608);      // 16,777,216 bf16
    unsigned short* wpad = (unsigned short*)(ws + 16777216);     // conv0 weights
    unsigned short* whp  = (unsigned short*)(ws + 16887808);     // packed hi (82,944)
    float* raw   = ws + 16929280;        // 512 (4 layers x 128)
    float* part  = ws + 17825792;        // NPART*96*64 floats
    float* cntp  = part + 3145728;       // NPART*96 floats

    hipMemsetAsync(raw, 0, 512 * sizeof(float), stream);
    prep_w_k<<<332, 256, 0, stream>>>(conv0_w, convs_w, wpad, whp);

    // layer 0: data(fp32) -> bufA, raw sums -> raw[0..127]
    conv0_k<<<512, 512, 0, stream>>>(data, wpad, bufA, raw);
    // layer 1: bufA -> bufB (stats fused from raw)
    conv_slab_k<<<512, 1024, 0, stream>>>(bufA, whp, raw, bufB, raw + 128);
    // layer 2: bufB -> bufA
    conv_slab_k<<<512, 1024, 0, stream>>>(bufB, whp + 27648, raw + 128, bufA, raw + 256);
    // layer 3: bufA -> bufB
    conv_slab_k<<<512, 1024, 0, stream>>>(bufA, whp + 2 * 27648, raw + 256, bufB, raw + 384);

    // ROI pooling GEMM (stats fused from raw+384) -> partials + counts
    pool_mfma_k<<<NPART, 256, 0, stream>>>(bufB, raw + 384, mask, part, cntp);

    // per-ROI partial reduction + MLPs
    mlp_k<<<180, 256, 0, stream>>>(part, cntp, sw1, sb1, sw2, sb2,
                                   pw1, pb1, pw2, pb2, out);
}